// Round 6
// baseline (1464.353 us; speedup 1.0000x reference)
//
#include <hip/hip_runtime.h>

#define BN_EPS 1e-3f

typedef __attribute__((ext_vector_type(8))) short short8;
typedef __attribute__((ext_vector_type(4))) float float4v;

#define NREP 16  // BN stat replicas (atomic contention spread)

__device__ __forceinline__ short f2bf(float f) {
    unsigned u = __float_as_uint(f);
    unsigned r = (u + 0x7FFFu + ((u >> 16) & 1u)) >> 16;
    return (short)r;
}

// ---------------- small utility kernels ----------------

__global__ __launch_bounds__(256) void zero_kernel(float* p, int n) {
    int i = blockIdx.x * 256 + threadIdx.x;
    if (i < n) p[i] = 0.f;
}

__global__ __launch_bounds__(256) void copy_kernel(const float* __restrict__ in,
                                                   float* __restrict__ out, int n) {
    int i = blockIdx.x * 256 + threadIdx.x;
    if (i < n) out[i] = in[i];
}

// coords rows are (b, z, y, x); xyz = (x,y,z) * (voxel*stride) + (0,-40,-3)
__global__ __launch_bounds__(256) void xyz_kernel(const int* __restrict__ coords,
                                                  float* __restrict__ out, int N,
                                                  float sx, float sy, float sz) {
    int n = blockIdx.x * 256 + threadIdx.x;
    if (n >= N) return;
    int4 c = ((const int4*)coords)[n];  // x=b, y=z, z=y, w=x
    out[n * 3 + 0] = c.w * sx;
    out[n * 3 + 1] = c.z * sy - 40.0f;
    out[n * 3 + 2] = c.y * sz - 3.0f;
}

// f0 (N x 4 fp32) -> bf16 padded (N x 32)
__global__ __launch_bounds__(256) void convert_f0(const float* __restrict__ f,
                                                  short* __restrict__ dst, int N) {
    int i = blockIdx.x * 256 + threadIdx.x;
    if (i >= N * 32) return;
    int c = i & 31, n = i >> 5;
    dst[i] = (c < 4) ? f2bf(f[n * 4 + c]) : (short)0;
}

// ---------------- all-layer weight prep: W [K][CIN][COUT] fp32 -> Wt [K][COUT][CHP] bf16 ----
struct PrepAll {
    const float* src[14];
    short* dst[14];
    int K[14];
    int CI[14];
    int CO[14];
    int CHP[14];
    int cum[15];
};

__global__ __launch_bounds__(256) void prep_all_kernel(PrepAll d) {
    int i = blockIdx.x * 256 + threadIdx.x;
    if (i >= d.cum[14]) return;
    int l = 0;
    while (l < 13 && i >= d.cum[l + 1]) ++l;
    int j = i - d.cum[l];
    int chp = d.CHP[l];
    int ci = j % chp;
    int co = (j / chp) % d.CO[l];
    int k = j / (chp * d.CO[l]);
    float v = (ci < d.CI[l]) ? d.src[l][((size_t)k * d.CI[l] + ci) * d.CO[l] + co] : 0.f;
    d.dst[l][j] = f2bf(v);
}

// ---------------- MFMA sparse conv, 1 wave/block, 16 rows x COUT cols ----------------
// feat: bf16 [Nin][CHP]; Wt: bf16 [K][COUT][CHP]; rb: [K][N] (-1 = none)
// Single column pass (CT = COUT/16) halves gather traffic vs 2 col-blocks.
// A-gather ring depth AD (prefetch distance AD-1) for memory-level parallelism:
// ~(AD-1)*CH*16B in flight per wave. rb loads + preact stores are non-temporal
// so streams don't evict the feat array from L2 (R5: 50% gather L2 miss).
template <int CH, int CT, int COUT, int K, int AD>
__global__ __launch_bounds__(64, 2) void sconv_mfma(const short* __restrict__ feat,
                                                    const int* __restrict__ rb,
                                                    const short* __restrict__ Wt,
                                                    float* __restrict__ out,
                                                    float* __restrict__ stats, int N) {
    constexpr int CHP = CH * 32;
    constexpr int PD = (AD - 1 < K) ? AD - 1 : K;  // prefetch distance
    const int lane = threadIdx.x;
    const int quad = lane >> 4;
    const int l16 = lane & 15;
    const int m0 = blockIdx.x * 16;
    const int row = m0 + l16;
    const int rowc = (row < N - 1) ? row : (N - 1);
    const bool rvalid = (row < N);

    // preload all rulebook indices (non-temporal: rb is streamed once)
    int idx[K];
#pragma unroll
    for (int k = 0; k < K; ++k) idx[k] = __builtin_nontemporal_load(&rb[(size_t)k * N + rowc]);

    const short* fquad = feat + quad * 8;
    const short* wbase = Wt + (size_t)l16 * CHP + quad * 8;

    short8 a[AD][CH];  // gather ring

    auto loadA = [&](int slot, int k) {
        int ix = idx[k];
        bool v = rvalid && (ix >= 0);
        int cix = ix < 0 ? 0 : ix;
        const short* p = fquad + (size_t)cix * CHP;
#pragma unroll
        for (int c = 0; c < CH; ++c) {
            short8 t = *(const short8*)(p + c * 32);
            a[slot][c] = v ? t : (short8)0;
        }
    };

    float4v acc[CT];
#pragma unroll
    for (int t = 0; t < CT; ++t) acc[t] = (float4v)0.f;

#pragma unroll
    for (int d = 0; d < PD; ++d) loadA(d, d);

#pragma unroll
    for (int k = 0; k < K; ++k) {
        if (k + PD < K) loadA((k + PD) % AD, k + PD);
        // B: single-buffered direct loads (L1/L2-hot, reused by every block)
        short8 b[CH][CT];
        const short* wk = wbase + (size_t)k * COUT * CHP;
#pragma unroll
        for (int t = 0; t < CT; ++t)
#pragma unroll
            for (int c = 0; c < CH; ++c)
                b[c][t] = *(const short8*)(wk + (size_t)t * 16 * CHP + c * 32);
#pragma unroll
        for (int c = 0; c < CH; ++c)
#pragma unroll
            for (int t = 0; t < CT; ++t)
                acc[t] = __builtin_amdgcn_mfma_f32_16x16x32_bf16(a[k % AD][c], b[c][t], acc[t], 0,
                                                                 0, 0);
    }

    // D layout: col = lane&15, row = quad*4 + reg. Non-temporal stores: preact is
    // consumed once by bn_apply; keep it out of L2 so feat stays resident.
    float* st = stats + (size_t)(blockIdx.x & (NREP - 1)) * 128;
#pragma unroll
    for (int t = 0; t < CT; ++t) {
        int col = t * 16 + l16;
#pragma unroll
        for (int r = 0; r < 4; ++r) {
            int orow = m0 + quad * 4 + r;
            if (orow < N) __builtin_nontemporal_store(acc[t][r], &out[(size_t)orow * COUT + col]);
        }
        // fused BN stats (rows >= N contributed exact zeros)
        float s = acc[t][0] + acc[t][1] + acc[t][2] + acc[t][3];
        float ss = acc[t][0] * acc[t][0] + acc[t][1] * acc[t][1] + acc[t][2] * acc[t][2] +
                   acc[t][3] * acc[t][3];
        s += __shfl_xor(s, 16);
        s += __shfl_xor(s, 32);
        ss += __shfl_xor(ss, 16);
        ss += __shfl_xor(ss, 32);
        if (lane < 16) {
            atomicAdd(&st[col], s);
            atomicAdd(&st[64 + col], ss);
        }
    }
}

// ---------------- BN apply + ReLU; replica-reduce in LDS prologue ----------------
// writes bf16 (padded to CHPN) for next layer and/or fp32 output
template <int COUT, int CHPN, bool F32OUT, bool BFOUT>
__global__ __launch_bounds__(256) void bn_apply(const float* __restrict__ x,
                                                const float* __restrict__ stats,
                                                const float* __restrict__ g,
                                                const float* __restrict__ b,
                                                float* __restrict__ fout,
                                                short* __restrict__ bfout, int N) {
    constexpr int CW = BFOUT ? CHPN : COUT;
    __shared__ float ssc[COUT];
    __shared__ float ssh[COUT];
    int tid = threadIdx.x;
    if (tid < COUT) {
        float s = 0.f, q = 0.f;
#pragma unroll
        for (int r = 0; r < NREP; ++r) {
            s += stats[r * 128 + tid];
            q += stats[r * 128 + 64 + tid];
        }
        float inv = 1.0f / (float)N;
        float m = s * inv;
        float v = q * inv - m * m;
        float sc = g[tid] / sqrtf(v + BN_EPS);
        ssc[tid] = sc;
        ssh[tid] = b[tid] - m * sc;
    }
    __syncthreads();
    long i = (long)blockIdx.x * 256 + tid;
    if (i >= (long)N * CW) return;
    int c = (int)(i % CW);
    long n = i / CW;
    float y = 0.f;
    if (c < COUT) {
        y = fmaxf(__builtin_nontemporal_load(&x[n * COUT + c]) * ssc[c] + ssh[c], 0.f);
        if (F32OUT) __builtin_nontemporal_store(y, &fout[n * COUT + c]);
    }
    if (BFOUT) bfout[n * CHPN + c] = f2bf(y);
}

// ---------------- host helpers ----------------

template <int CH, int CT, int COUT, int K, int AD>
static void conv(const short* fin, const int* rb, const short* wt, float* preact, float* stats,
                 int N, hipStream_t stream) {
    dim3 grid((N + 15) / 16);
    hipLaunchKernelGGL((sconv_mfma<CH, CT, COUT, K, AD>), grid, dim3(64), 0, stream, fin, rb, wt,
                       preact, stats, N);
}

template <int COUT, int CHPN, bool F32OUT, bool BFOUT>
static void apply(const float* preact, const float* stats, const float* g, const float* b,
                  float* fout, short* bfout, int N, hipStream_t stream) {
    constexpr int CW = BFOUT ? CHPN : COUT;
    int blocks = (int)(((long)N * CW + 255) / 256);
    hipLaunchKernelGGL((bn_apply<COUT, CHPN, F32OUT, BFOUT>), dim3(blocks), dim3(256), 0, stream,
                       preact, stats, g, b, fout, bfout, N);
}

extern "C" void kernel_launch(void* const* d_in, const int* in_sizes, int n_in, void* d_out,
                              int out_size, void* d_ws, size_t ws_size, hipStream_t stream) {
    const float* features = (const float*)d_in[0];
    const float* W[14];
    const float* G[14];
    const float* Bb[14];
    for (int i = 0; i < 14; ++i) {
        W[i] = (const float*)d_in[1 + 3 * i];
        G[i] = (const float*)d_in[2 + 3 * i];
        Bb[i] = (const float*)d_in[3 + 3 * i];
    }
    const int* coords0 = (const int*)d_in[43];
    const int* coords1 = (const int*)d_in[44];
    const int* coords2 = (const int*)d_in[45];
    const int* coords3 = (const int*)d_in[46];
    const int* rb0 = (const int*)d_in[47];
    const int* rbc1 = (const int*)d_in[48];
    const int* rb1 = (const int*)d_in[49];
    const int* rbc2 = (const int*)d_in[50];
    const int* rb2 = (const int*)d_in[51];
    const int* rbc3 = (const int*)d_in[52];
    const int* rb3 = (const int*)d_in[53];
    const int* rbc4 = (const int*)d_in[54];

    const int N0 = in_sizes[0] / 4;
    const int N1 = in_sizes[44] / 4;
    const int N2 = in_sizes[45] / 4;
    const int N3 = in_sizes[46] / 4;
    const int N4 = in_sizes[54] / 3;

    float* out = (float*)d_out;
    long off = 0;
    float* xyz0 = out + off; off += (long)N0 * 3;
    float* f0   = out + off; off += (long)N0 * 4;
    float* xyz1 = out + off; off += (long)N1 * 3;
    float* f1   = out + off; off += (long)N1 * 32;
    float* xyz2 = out + off; off += (long)N2 * 3;
    float* f2   = out + off; off += (long)N2 * 64;
    float* xyz3 = out + off; off += (long)N3 * 3;
    float* f3   = out + off; off += (long)N3 * 64;
    float* f4   = out + off;

    long maxN = N0;
    if (N1 > maxN) maxN = N1;
    if (N2 > maxN) maxN = N2;
    if (N3 > maxN) maxN = N3;
    if (N4 > maxN) maxN = N4;

    // workspace layout
    float* preact = (float*)d_ws;                         // maxN*64 fp32
    float* statsBase = preact + (size_t)maxN * 64;        // 14 * NREP * 128 fp32
    short* bfA = (short*)(statsBase + 14 * NREP * 128);   // maxN*64 bf16
    short* bfB = bfA + (size_t)maxN * 64;                 // maxN*64 bf16
    short* wtBase = bfB + (size_t)maxN * 64;              // transposed bf16 weights

    static const int KK[14] = {27, 27, 27, 27, 27, 27, 27, 27, 27, 27, 27, 27, 27, 3};
    static const int CI[14] = {4, 16, 16, 32, 32, 32, 64, 64, 64, 64, 64, 64, 64, 64};
    static const int CO[14] = {16, 16, 32, 32, 32, 64, 64, 64, 64, 64, 64, 64, 64, 64};
    short* WT[14];
    PrepAll pd;
    {
        size_t o = 0;
        int cum = 0;
        for (int l = 0; l < 14; ++l) {
            WT[l] = wtBase + o;
            int chp = CI[l] <= 32 ? 32 : 64;
            pd.src[l] = W[l];
            pd.dst[l] = WT[l];
            pd.K[l] = KK[l];
            pd.CI[l] = CI[l];
            pd.CO[l] = CO[l];
            pd.CHP[l] = chp;
            pd.cum[l] = cum;
            cum += KK[l] * CO[l] * chp;
            o += (size_t)KK[l] * CO[l] * chp;
        }
        pd.cum[14] = cum;
    }

    // zero BN stat slots
    int nstats = 14 * NREP * 128;
    hipLaunchKernelGGL(zero_kernel, dim3((nstats + 255) / 256), dim3(256), 0, stream, statsBase,
                       nstats);

    // prep all weights in one launch
    hipLaunchKernelGGL(prep_all_kernel, dim3((pd.cum[14] + 255) / 256), dim3(256), 0, stream, pd);

    // passthrough outputs
    hipLaunchKernelGGL(copy_kernel, dim3((N0 * 4 + 255) / 256), dim3(256), 0, stream, features, f0,
                       N0 * 4);
    hipLaunchKernelGGL(xyz_kernel, dim3((N0 + 255) / 256), dim3(256), 0, stream, coords0, xyz0, N0,
                       0.05f, 0.05f, 0.1f);
    hipLaunchKernelGGL(xyz_kernel, dim3((N1 + 255) / 256), dim3(256), 0, stream, coords1, xyz1, N1,
                       0.1f, 0.1f, 0.2f);
    hipLaunchKernelGGL(xyz_kernel, dim3((N2 + 255) / 256), dim3(256), 0, stream, coords2, xyz2, N2,
                       0.2f, 0.2f, 0.4f);
    hipLaunchKernelGGL(xyz_kernel, dim3((N3 + 255) / 256), dim3(256), 0, stream, coords3, xyz3, N3,
                       0.4f, 0.4f, 0.8f);

    // f0 -> bf16 padded
    hipLaunchKernelGGL(convert_f0, dim3((N0 * 32 + 255) / 256), dim3(256), 0, stream, features,
                       bfA, N0);

    float* st = statsBase;
#define STAT(l) (st + (size_t)(l)*NREP * 128)

    // stage 1
    conv<1, 1, 16, 27, 6>(bfA, rb0, WT[0], preact, STAT(0), N0, stream);
    apply<16, 32, false, true>(preact, STAT(0), G[0], Bb[0], nullptr, bfB, N0, stream);
    conv<1, 1, 16, 27, 6>(bfB, rb0, WT[1], preact, STAT(1), N0, stream);
    apply<16, 32, false, true>(preact, STAT(1), G[1], Bb[1], nullptr, bfA, N0, stream);
    conv<1, 2, 32, 27, 6>(bfA, rbc1, WT[2], preact, STAT(2), N1, stream);
    apply<32, 32, true, true>(preact, STAT(2), G[2], Bb[2], f1, bfB, N1, stream);
    // stage 2
    conv<1, 2, 32, 27, 6>(bfB, rb1, WT[3], preact, STAT(3), N1, stream);
    apply<32, 32, false, true>(preact, STAT(3), G[3], Bb[3], nullptr, bfA, N1, stream);
    conv<1, 2, 32, 27, 6>(bfA, rb1, WT[4], preact, STAT(4), N1, stream);
    apply<32, 32, false, true>(preact, STAT(4), G[4], Bb[4], nullptr, bfB, N1, stream);
    conv<1, 4, 64, 27, 6>(bfB, rbc2, WT[5], preact, STAT(5), N2, stream);
    apply<64, 64, true, true>(preact, STAT(5), G[5], Bb[5], f2, bfA, N2, stream);
    // stage 3
    conv<2, 4, 64, 27, 6>(bfA, rb2, WT[6], preact, STAT(6), N2, stream);
    apply<64, 64, false, true>(preact, STAT(6), G[6], Bb[6], nullptr, bfB, N2, stream);
    conv<2, 4, 64, 27, 6>(bfB, rb2, WT[7], preact, STAT(7), N2, stream);
    apply<64, 64, false, true>(preact, STAT(7), G[7], Bb[7], nullptr, bfA, N2, stream);
    conv<2, 4, 64, 27, 6>(bfA, rb2, WT[8], preact, STAT(8), N2, stream);
    apply<64, 64, false, true>(preact, STAT(8), G[8], Bb[8], nullptr, bfB, N2, stream);
    conv<2, 4, 64, 27, 6>(bfB, rbc3, WT[9], preact, STAT(9), N3, stream);
    apply<64, 64, true, true>(preact, STAT(9), G[9], Bb[9], f3, bfA, N3, stream);
    // stage 4
    conv<2, 4, 64, 27, 6>(bfA, rb3, WT[10], preact, STAT(10), N3, stream);
    apply<64, 64, false, true>(preact, STAT(10), G[10], Bb[10], nullptr, bfB, N3, stream);
    conv<2, 4, 64, 27, 6>(bfB, rb3, WT[11], preact, STAT(11), N3, stream);
    apply<64, 64, false, true>(preact, STAT(11), G[11], Bb[11], nullptr, bfA, N3, stream);
    conv<2, 4, 64, 27, 6>(bfA, rb3, WT[12], preact, STAT(12), N3, stream);
    apply<64, 64, false, true>(preact, STAT(12), G[12], Bb[12], nullptr, bfB, N3, stream);
    conv<2, 4, 64, 3, 3>(bfB, rbc4, WT[13], preact, STAT(13), N4, stream);
    apply<64, 64, true, false>(preact, STAT(13), G[13], Bb[13], f4, nullptr, N4, stream);
#undef STAT
}

// Round 7
// 1383.815 us; speedup vs baseline: 1.0582x; 1.0582x over previous
//
#include <hip/hip_runtime.h>

#define BN_EPS 1e-3f

typedef __attribute__((ext_vector_type(8))) short short8;
typedef __attribute__((ext_vector_type(4))) float float4v;

#define NREP 16  // BN stat replicas (atomic contention spread)

__device__ __forceinline__ short f2bf(float f) {
    unsigned u = __float_as_uint(f);
    unsigned r = (u + 0x7FFFu + ((u >> 16) & 1u)) >> 16;
    return (short)r;
}

// ---------------- small utility kernels ----------------

__global__ __launch_bounds__(256) void zero_kernel(float* p, int n) {
    int i = blockIdx.x * 256 + threadIdx.x;
    if (i < n) p[i] = 0.f;
}

__global__ __launch_bounds__(256) void copy_kernel(const float* __restrict__ in,
                                                   float* __restrict__ out, int n) {
    int i = blockIdx.x * 256 + threadIdx.x;
    if (i < n) out[i] = in[i];
}

// coords rows are (b, z, y, x); xyz = (x,y,z) * (voxel*stride) + (0,-40,-3)
__global__ __launch_bounds__(256) void xyz_kernel(const int* __restrict__ coords,
                                                  float* __restrict__ out, int N,
                                                  float sx, float sy, float sz) {
    int n = blockIdx.x * 256 + threadIdx.x;
    if (n >= N) return;
    int4 c = ((const int4*)coords)[n];  // x=b, y=z, z=y, w=x
    out[n * 3 + 0] = c.w * sx;
    out[n * 3 + 1] = c.z * sy - 40.0f;
    out[n * 3 + 2] = c.y * sz - 3.0f;
}

// f0 (N x 4 fp32) -> bf16 padded (N x 32)
__global__ __launch_bounds__(256) void convert_f0(const float* __restrict__ f,
                                                  short* __restrict__ dst, int N) {
    int i = blockIdx.x * 256 + threadIdx.x;
    if (i >= N * 32) return;
    int c = i & 31, n = i >> 5;
    dst[i] = (c < 4) ? f2bf(f[n * 4 + c]) : (short)0;
}

// ---------------- all-layer weight prep: W [K][CIN][COUT] fp32 -> Wt [K][COUT][CHP] bf16 ----
struct PrepAll {
    const float* src[14];
    short* dst[14];
    int K[14];
    int CI[14];
    int CO[14];
    int CHP[14];
    int cum[15];
};

__global__ __launch_bounds__(256) void prep_all_kernel(PrepAll d) {
    int i = blockIdx.x * 256 + threadIdx.x;
    if (i >= d.cum[14]) return;
    int l = 0;
    while (l < 13 && i >= d.cum[l + 1]) ++l;
    int j = i - d.cum[l];
    int chp = d.CHP[l];
    int ci = j % chp;
    int co = (j / chp) % d.CO[l];
    int k = j / (chp * d.CO[l]);
    float v = (ci < d.CI[l]) ? d.src[l][((size_t)k * d.CI[l] + ci) * d.CO[l] + co] : 0.f;
    d.dst[l][j] = f2bf(v);
}

// ---------------- register-pipelined MFMA sparse conv helpers ----------------
// All loop structure is TEMPLATE-RECURSED so every array index is a compile-time
// constant -> SROA must keep rings in VGPRs. (R4-R6: #pragma unroll failed on the
// K=27 body, dynamic k%AD indexing demoted rings to scratch: VGPR=52, WRITE=31MB
// of spill traffic, 15K cyc/k-step.)

template <int CH>
__device__ __forceinline__ void loadA(short8 (&dst)[CH], const short* fquad, int ix, bool rvalid) {
    bool v = rvalid && (ix >= 0);
    const short* p = fquad + (size_t)(ix < 0 ? 0 : ix) * (CH * 32);
#pragma unroll
    for (int c = 0; c < CH; ++c) {
        short8 t = *(const short8*)(p + c * 32);
        dst[c] = v ? t : (short8)0;
    }
}

template <int CH, int CT, int COUT>
__device__ __forceinline__ void loadB(short8 (&dst)[CH][CT], const short* wk) {
#pragma unroll
    for (int t = 0; t < CT; ++t)
#pragma unroll
        for (int c = 0; c < CH; ++c)
            dst[c][t] = *(const short8*)(wk + (size_t)t * 16 * (CH * 32) + c * 32);
}

template <int d, int PD, int AD, int CH, int K>
__device__ __forceinline__ void prologueA(short8 (&a)[AD][CH], const int (&idx)[K],
                                          const short* fquad, bool rvalid) {
    if constexpr (d < PD) {
        loadA<CH>(a[d], fquad, idx[d], rvalid);
        prologueA<d + 1, PD, AD, CH, K>(a, idx, fquad, rvalid);
    }
}

template <int k, int K, int AD, int PD, int CH, int CT, int COUT>
__device__ __forceinline__ void kloop(short8 (&a)[AD][CH], short8 (&b)[2][CH][CT],
                                      float4v (&acc)[CT], const int (&idx)[K],
                                      const short* fquad, const short* wbase, bool rvalid) {
    if constexpr (k < K) {
        if constexpr (k + PD < K) loadA<CH>(a[(k + PD) % AD], fquad, idx[k + PD], rvalid);
        if constexpr (k + 1 < K)
            loadB<CH, CT, COUT>(b[(k + 1) & 1], wbase + (size_t)(k + 1) * COUT * CH * 32);
#pragma unroll
        for (int c = 0; c < CH; ++c)
#pragma unroll
            for (int t = 0; t < CT; ++t)
                acc[t] = __builtin_amdgcn_mfma_f32_16x16x32_bf16(a[k % AD][c], b[k & 1][c][t],
                                                                 acc[t], 0, 0, 0);
        kloop<k + 1, K, AD, PD, CH, CT, COUT>(a, b, acc, idx, fquad, wbase, rvalid);
    }
}

template <int j, int K>
__device__ __forceinline__ void loadIdx(int (&idx)[K], const int* __restrict__ rb, int rowc,
                                        int N) {
    if constexpr (j < K) {
        idx[j] = __builtin_nontemporal_load(&rb[(size_t)j * N + rowc]);
        loadIdx<j + 1, K>(idx, rb, rowc, N);
    }
}

// feat: bf16 [Nin][CHP]; Wt: bf16 [K][COUT][CHP]; rb: [K][N] (-1 = none)
// 1 wave/block, 16 rows x COUT cols. BN sum/sumsq fused (NREP replicas).
template <int CH, int CT, int COUT, int K, int AD>
__global__ __launch_bounds__(64, 2) void sconv_mfma(const short* __restrict__ feat,
                                                    const int* __restrict__ rb,
                                                    const short* __restrict__ Wt,
                                                    float* __restrict__ out,
                                                    float* __restrict__ stats, int N) {
    constexpr int CHP = CH * 32;
    constexpr int PD = AD - 1;  // prefetch distance
    const int lane = threadIdx.x;
    const int quad = lane >> 4;
    const int l16 = lane & 15;
    const int m0 = blockIdx.x * 16;
    const int row = m0 + l16;
    const int rowc = (row < N - 1) ? row : (N - 1);
    const bool rvalid = (row < N);

    int idx[K];
    loadIdx<0, K>(idx, rb, rowc, N);

    const short* fquad = feat + quad * 8;
    const short* wbase = Wt + (size_t)l16 * CHP + quad * 8;

    short8 a[AD][CH];
    short8 b[2][CH][CT];
    float4v acc[CT];
#pragma unroll
    for (int t = 0; t < CT; ++t) acc[t] = (float4v)0.f;

    prologueA<0, PD, AD, CH, K>(a, idx, fquad, rvalid);
    loadB<CH, CT, COUT>(b[0], wbase);
    kloop<0, K, AD, PD, CH, CT, COUT>(a, b, acc, idx, fquad, wbase, rvalid);

    // D layout: col = lane&15, row = quad*4 + reg. NT stores: preact consumed once.
    float* st = stats + (size_t)(blockIdx.x & (NREP - 1)) * 128;
#pragma unroll
    for (int t = 0; t < CT; ++t) {
        int col = t * 16 + l16;
#pragma unroll
        for (int r = 0; r < 4; ++r) {
            int orow = m0 + quad * 4 + r;
            if (orow < N) __builtin_nontemporal_store(acc[t][r], &out[(size_t)orow * COUT + col]);
        }
        // fused BN stats (rows >= N contributed exact zeros)
        float s = acc[t][0] + acc[t][1] + acc[t][2] + acc[t][3];
        float ss = acc[t][0] * acc[t][0] + acc[t][1] * acc[t][1] + acc[t][2] * acc[t][2] +
                   acc[t][3] * acc[t][3];
        s += __shfl_xor(s, 16);
        s += __shfl_xor(s, 32);
        ss += __shfl_xor(ss, 16);
        ss += __shfl_xor(ss, 32);
        if (lane < 16) {
            atomicAdd(&st[col], s);
            atomicAdd(&st[64 + col], ss);
        }
    }
}

// ---------------- BN apply + ReLU; replica-reduce in LDS prologue ----------------
template <int COUT, int CHPN, bool F32OUT, bool BFOUT>
__global__ __launch_bounds__(256) void bn_apply(const float* __restrict__ x,
                                                const float* __restrict__ stats,
                                                const float* __restrict__ g,
                                                const float* __restrict__ b,
                                                float* __restrict__ fout,
                                                short* __restrict__ bfout, int N) {
    constexpr int CW = BFOUT ? CHPN : COUT;
    __shared__ float ssc[COUT];
    __shared__ float ssh[COUT];
    int tid = threadIdx.x;
    if (tid < COUT) {
        float s = 0.f, q = 0.f;
#pragma unroll
        for (int r = 0; r < NREP; ++r) {
            s += stats[r * 128 + tid];
            q += stats[r * 128 + 64 + tid];
        }
        float inv = 1.0f / (float)N;
        float m = s * inv;
        float v = q * inv - m * m;
        float sc = g[tid] / sqrtf(v + BN_EPS);
        ssc[tid] = sc;
        ssh[tid] = b[tid] - m * sc;
    }
    __syncthreads();
    long i = (long)blockIdx.x * 256 + tid;
    if (i >= (long)N * CW) return;
    int c = (int)(i % CW);
    long n = i / CW;
    float y = 0.f;
    if (c < COUT) {
        y = fmaxf(__builtin_nontemporal_load(&x[n * COUT + c]) * ssc[c] + ssh[c], 0.f);
        if (F32OUT) __builtin_nontemporal_store(y, &fout[n * COUT + c]);
    }
    if (BFOUT) bfout[n * CHPN + c] = f2bf(y);
}

// ---------------- host helpers ----------------

template <int CH, int CT, int COUT, int K, int AD>
static void conv(const short* fin, const int* rb, const short* wt, float* preact, float* stats,
                 int N, hipStream_t stream) {
    dim3 grid((N + 15) / 16);
    hipLaunchKernelGGL((sconv_mfma<CH, CT, COUT, K, AD>), grid, dim3(64), 0, stream, fin, rb, wt,
                       preact, stats, N);
}

template <int COUT, int CHPN, bool F32OUT, bool BFOUT>
static void apply(const float* preact, const float* stats, const float* g, const float* b,
                  float* fout, short* bfout, int N, hipStream_t stream) {
    constexpr int CW = BFOUT ? CHPN : COUT;
    int blocks = (int)(((long)N * CW + 255) / 256);
    hipLaunchKernelGGL((bn_apply<COUT, CHPN, F32OUT, BFOUT>), dim3(blocks), dim3(256), 0, stream,
                       preact, stats, g, b, fout, bfout, N);
}

extern "C" void kernel_launch(void* const* d_in, const int* in_sizes, int n_in, void* d_out,
                              int out_size, void* d_ws, size_t ws_size, hipStream_t stream) {
    const float* features = (const float*)d_in[0];
    const float* W[14];
    const float* G[14];
    const float* Bb[14];
    for (int i = 0; i < 14; ++i) {
        W[i] = (const float*)d_in[1 + 3 * i];
        G[i] = (const float*)d_in[2 + 3 * i];
        Bb[i] = (const float*)d_in[3 + 3 * i];
    }
    const int* coords0 = (const int*)d_in[43];
    const int* coords1 = (const int*)d_in[44];
    const int* coords2 = (const int*)d_in[45];
    const int* coords3 = (const int*)d_in[46];
    const int* rb0 = (const int*)d_in[47];
    const int* rbc1 = (const int*)d_in[48];
    const int* rb1 = (const int*)d_in[49];
    const int* rbc2 = (const int*)d_in[50];
    const int* rb2 = (const int*)d_in[51];
    const int* rbc3 = (const int*)d_in[52];
    const int* rb3 = (const int*)d_in[53];
    const int* rbc4 = (const int*)d_in[54];

    const int N0 = in_sizes[0] / 4;
    const int N1 = in_sizes[44] / 4;
    const int N2 = in_sizes[45] / 4;
    const int N3 = in_sizes[46] / 4;
    const int N4 = in_sizes[54] / 3;

    float* out = (float*)d_out;
    long off = 0;
    float* xyz0 = out + off; off += (long)N0 * 3;
    float* f0   = out + off; off += (long)N0 * 4;
    float* xyz1 = out + off; off += (long)N1 * 3;
    float* f1   = out + off; off += (long)N1 * 32;
    float* xyz2 = out + off; off += (long)N2 * 3;
    float* f2   = out + off; off += (long)N2 * 64;
    float* xyz3 = out + off; off += (long)N3 * 3;
    float* f3   = out + off; off += (long)N3 * 64;
    float* f4   = out + off;

    long maxN = N0;
    if (N1 > maxN) maxN = N1;
    if (N2 > maxN) maxN = N2;
    if (N3 > maxN) maxN = N3;
    if (N4 > maxN) maxN = N4;

    // workspace layout
    float* preact = (float*)d_ws;                         // maxN*64 fp32
    float* statsBase = preact + (size_t)maxN * 64;        // 14 * NREP * 128 fp32
    short* bfA = (short*)(statsBase + 14 * NREP * 128);   // maxN*64 bf16
    short* bfB = bfA + (size_t)maxN * 64;                 // maxN*64 bf16
    short* wtBase = bfB + (size_t)maxN * 64;              // transposed bf16 weights

    static const int KK[14] = {27, 27, 27, 27, 27, 27, 27, 27, 27, 27, 27, 27, 27, 3};
    static const int CI[14] = {4, 16, 16, 32, 32, 32, 64, 64, 64, 64, 64, 64, 64, 64};
    static const int CO[14] = {16, 16, 32, 32, 32, 64, 64, 64, 64, 64, 64, 64, 64, 64};
    short* WT[14];
    PrepAll pd;
    {
        size_t o = 0;
        int cum = 0;
        for (int l = 0; l < 14; ++l) {
            WT[l] = wtBase + o;
            int chp = CI[l] <= 32 ? 32 : 64;
            pd.src[l] = W[l];
            pd.dst[l] = WT[l];
            pd.K[l] = KK[l];
            pd.CI[l] = CI[l];
            pd.CO[l] = CO[l];
            pd.CHP[l] = chp;
            pd.cum[l] = cum;
            cum += KK[l] * CO[l] * chp;
            o += (size_t)KK[l] * CO[l] * chp;
        }
        pd.cum[14] = cum;
    }

    // zero BN stat slots
    int nstats = 14 * NREP * 128;
    hipLaunchKernelGGL(zero_kernel, dim3((nstats + 255) / 256), dim3(256), 0, stream, statsBase,
                       nstats);

    // prep all weights in one launch
    hipLaunchKernelGGL(prep_all_kernel, dim3((pd.cum[14] + 255) / 256), dim3(256), 0, stream, pd);

    // passthrough outputs
    hipLaunchKernelGGL(copy_kernel, dim3((N0 * 4 + 255) / 256), dim3(256), 0, stream, features, f0,
                       N0 * 4);
    hipLaunchKernelGGL(xyz_kernel, dim3((N0 + 255) / 256), dim3(256), 0, stream, coords0, xyz0, N0,
                       0.05f, 0.05f, 0.1f);
    hipLaunchKernelGGL(xyz_kernel, dim3((N1 + 255) / 256), dim3(256), 0, stream, coords1, xyz1, N1,
                       0.1f, 0.1f, 0.2f);
    hipLaunchKernelGGL(xyz_kernel, dim3((N2 + 255) / 256), dim3(256), 0, stream, coords2, xyz2, N2,
                       0.2f, 0.2f, 0.4f);
    hipLaunchKernelGGL(xyz_kernel, dim3((N3 + 255) / 256), dim3(256), 0, stream, coords3, xyz3, N3,
                       0.4f, 0.4f, 0.8f);

    // f0 -> bf16 padded
    hipLaunchKernelGGL(convert_f0, dim3((N0 * 32 + 255) / 256), dim3(256), 0, stream, features,
                       bfA, N0);

    float* st = statsBase;
#define STAT(l) (st + (size_t)(l)*NREP * 128)

    // stage 1
    conv<1, 1, 16, 27, 4>(bfA, rb0, WT[0], preact, STAT(0), N0, stream);
    apply<16, 32, false, true>(preact, STAT(0), G[0], Bb[0], nullptr, bfB, N0, stream);
    conv<1, 1, 16, 27, 4>(bfB, rb0, WT[1], preact, STAT(1), N0, stream);
    apply<16, 32, false, true>(preact, STAT(1), G[1], Bb[1], nullptr, bfA, N0, stream);
    conv<1, 2, 32, 27, 4>(bfA, rbc1, WT[2], preact, STAT(2), N1, stream);
    apply<32, 32, true, true>(preact, STAT(2), G[2], Bb[2], f1, bfB, N1, stream);
    // stage 2
    conv<1, 2, 32, 27, 4>(bfB, rb1, WT[3], preact, STAT(3), N1, stream);
    apply<32, 32, false, true>(preact, STAT(3), G[3], Bb[3], nullptr, bfA, N1, stream);
    conv<1, 2, 32, 27, 4>(bfA, rb1, WT[4], preact, STAT(4), N1, stream);
    apply<32, 32, false, true>(preact, STAT(4), G[4], Bb[4], nullptr, bfB, N1, stream);
    conv<1, 4, 64, 27, 4>(bfB, rbc2, WT[5], preact, STAT(5), N2, stream);
    apply<64, 64, true, true>(preact, STAT(5), G[5], Bb[5], f2, bfA, N2, stream);
    // stage 3
    conv<2, 4, 64, 27, 4>(bfA, rb2, WT[6], preact, STAT(6), N2, stream);
    apply<64, 64, false, true>(preact, STAT(6), G[6], Bb[6], nullptr, bfB, N2, stream);
    conv<2, 4, 64, 27, 4>(bfB, rb2, WT[7], preact, STAT(7), N2, stream);
    apply<64, 64, false, true>(preact, STAT(7), G[7], Bb[7], nullptr, bfA, N2, stream);
    conv<2, 4, 64, 27, 4>(bfA, rb2, WT[8], preact, STAT(8), N2, stream);
    apply<64, 64, false, true>(preact, STAT(8), G[8], Bb[8], nullptr, bfB, N2, stream);
    conv<2, 4, 64, 27, 4>(bfB, rbc3, WT[9], preact, STAT(9), N3, stream);
    apply<64, 64, true, true>(preact, STAT(9), G[9], Bb[9], f3, bfA, N3, stream);
    // stage 4
    conv<2, 4, 64, 27, 4>(bfA, rb3, WT[10], preact, STAT(10), N3, stream);
    apply<64, 64, false, true>(preact, STAT(10), G[10], Bb[10], nullptr, bfB, N3, stream);
    conv<2, 4, 64, 27, 4>(bfB, rb3, WT[11], preact, STAT(11), N3, stream);
    apply<64, 64, false, true>(preact, STAT(11), G[11], Bb[11], nullptr, bfA, N3, stream);
    conv<2, 4, 64, 27, 4>(bfA, rb3, WT[12], preact, STAT(12), N3, stream);
    apply<64, 64, false, true>(preact, STAT(12), G[12], Bb[12], nullptr, bfB, N3, stream);
    conv<2, 4, 64, 3, 3>(bfB, rbc4, WT[13], preact, STAT(13), N4, stream);
    apply<64, 64, true, false>(preact, STAT(13), G[13], Bb[13], f4, nullptr, N4, stream);
#undef STAT
}

// Round 8
// 1138.313 us; speedup vs baseline: 1.2864x; 1.2157x over previous
//
#include <hip/hip_runtime.h>

#define BN_EPS 1e-3f
#define NREP 16  // BN stat replicas (atomic contention spread)

typedef __attribute__((ext_vector_type(8))) short short8;
typedef __attribute__((ext_vector_type(4))) float float4v;

__device__ __forceinline__ short f2bf(float f) {
    unsigned u = __float_as_uint(f);
    unsigned r = (u + 0x7FFFu + ((u >> 16) & 1u)) >> 16;
    return (short)r;
}

// s_waitcnt vmcnt(N), lgkm/exp untouched
template <int N>
__device__ __forceinline__ void waitcnt_vm() {
    __builtin_amdgcn_s_waitcnt(0xF70 | (N & 15) | ((N >> 4) << 14));
}

// async global -> LDS, 16B per lane. lds dst = wave-uniform base + lane*16.
__device__ __forceinline__ void dma16(const short* g, short* l) {
    __builtin_amdgcn_global_load_lds((const __attribute__((address_space(1))) void*)g,
                                     (__attribute__((address_space(3))) void*)l, 16, 0, 0);
}

// ---------------- small utility kernels ----------------

__global__ __launch_bounds__(256) void zero_kernel(float* p, int n) {
    int i = blockIdx.x * 256 + threadIdx.x;
    if (i < n) p[i] = 0.f;
}

__global__ __launch_bounds__(256) void copy_kernel(const float* __restrict__ in,
                                                   float* __restrict__ out, int n) {
    int i = blockIdx.x * 256 + threadIdx.x;
    if (i < n) out[i] = in[i];
}

// zero the "zero rows" (index maxN) of both bf16 buffers at both strides
__global__ __launch_bounds__(256) void zero_rows_kernel(short* a, short* b, long maxN) {
    int t = threadIdx.x;
    if (t < 32) a[maxN * 32 + t] = 0;
    else if (t < 96) a[maxN * 64 + (t - 32)] = 0;
    else if (t < 128) b[maxN * 32 + (t - 96)] = 0;
    else if (t < 192) b[maxN * 64 + (t - 128)] = 0;
}

// coords rows are (b, z, y, x); xyz = (x,y,z) * (voxel*stride) + (0,-40,-3)
__global__ __launch_bounds__(256) void xyz_kernel(const int* __restrict__ coords,
                                                  float* __restrict__ out, int N,
                                                  float sx, float sy, float sz) {
    int n = blockIdx.x * 256 + threadIdx.x;
    if (n >= N) return;
    int4 c = ((const int4*)coords)[n];  // x=b, y=z, z=y, w=x
    out[n * 3 + 0] = c.w * sx;
    out[n * 3 + 1] = c.z * sy - 40.0f;
    out[n * 3 + 2] = c.y * sz - 3.0f;
}

// f0 (N x 4 fp32) -> bf16 padded (N x 32)
__global__ __launch_bounds__(256) void convert_f0(const float* __restrict__ f,
                                                  short* __restrict__ dst, int N) {
    int i = blockIdx.x * 256 + threadIdx.x;
    if (i >= N * 32) return;
    int c = i & 31, n = i >> 5;
    dst[i] = (c < 4) ? f2bf(f[n * 4 + c]) : (short)0;
}

// ---------------- weight prep: W [K][CIN][COUT] fp32 -> Wt [K][CHP/8][CO][8] bf16 ----
// chunk-major so that DMA-contiguous LDS layout == conflict-free fragment layout.
struct PrepAll {
    const float* src[14];
    short* dst[14];
    int CI[14];
    int CO[14];
    int CHP[14];
    int cum[15];
};

__global__ __launch_bounds__(256) void prep_all_kernel(PrepAll d) {
    int i = blockIdx.x * 256 + threadIdx.x;
    if (i >= d.cum[14]) return;
    int l = 0;
    while (l < 13 && i >= d.cum[l + 1]) ++l;
    int j = i - d.cum[l];
    int CO = d.CO[l], CHP = d.CHP[l], CI = d.CI[l];
    int ci8 = j & 7;
    int r1 = j >> 3;
    int co = r1 % CO;
    int r2 = r1 / CO;
    int ch = r2 % (CHP / 8);
    int k = r2 / (CHP / 8);
    int ci = ch * 8 + ci8;
    float v = (ci < CI) ? d.src[l][((size_t)k * CI + ci) * CO + co] : 0.f;
    d.dst[l][j] = f2bf(v);
}

// ---------------- DMA-ring MFMA sparse conv: 1 wave/block, 16 rows x CO cols ----------
// feat: bf16 [Nin+1][CHP] (row zrow = zeros); Wt: bf16 [K][CHP/8][CO][8]; rb: [K][N].
// Ring of 3 LDS tiles, global_load_lds staging (NO register rings -> nothing to spill;
// R4-R7: every register-ring formulation was demoted to scratch, ~27MB spill/dispatch).
template <int CHP, int CO, int K>
__global__ __launch_bounds__(64) void sconv_dma(const short* __restrict__ feat,
                                                const int* __restrict__ rb,
                                                const short* __restrict__ Wt,
                                                float* __restrict__ out,
                                                float* __restrict__ stats, int N, int zrow) {
    constexpr int CH = CHP / 32;       // MFMA k-chunks per tile
    constexpr int CT = CO / 16;        // MFMA col tiles
    constexpr int ATILE = 16 * CHP;    // shorts
    constexpr int BTILE = CO * CHP;    // shorts
    constexpr int TILE = ATILE + BTILE;
    constexpr int NA = ATILE / 512;    // A DMA insts per tile (1KB each)
    constexpr int NB = BTILE / 512;    // B DMA insts per tile
    constexpr int ND = NA + NB;

    __shared__ __align__(16) short lds[3 * TILE];
    __shared__ int sIdx[K * 16];

    const int lane = threadIdx.x;
    const int quad = lane >> 4;
    const int l16 = lane & 15;
    const int m0 = blockIdx.x * 16;

    // stage rulebook indices to LDS (coalesced); rows >= N -> -1 -> zero row
    for (int e = lane; e < K * 16; e += 64) {
        int r = m0 + (e & 15);
        sIdx[e] = (r < N) ? rb[(size_t)(e >> 4) * N + r] : -1;
    }

    auto issueTile = [&](int kp, int slot) {
        short* base = lds + slot * TILE;
        if constexpr (NA == 1) {
            // lane = seg*16 + row -> LDS [4 seg][16 row][16B]
            int ix = sIdx[kp * 16 + (lane & 15)];
            dma16(feat + (size_t)(ix < 0 ? zrow : ix) * CHP + (lane >> 4) * 8, base);
        } else {
            // inst j: lane = rowlocal*8 + seg -> LDS [j][8 row][8 seg][16B]
            int ix0 = sIdx[kp * 16 + (lane >> 3)];
            int ix1 = sIdx[kp * 16 + 8 + (lane >> 3)];
            int seg = (lane & 7) * 8;
            dma16(feat + (size_t)(ix0 < 0 ? zrow : ix0) * CHP + seg, base);
            dma16(feat + (size_t)(ix1 < 0 ? zrow : ix1) * CHP + seg, base + 512);
        }
        const short* wk = Wt + (size_t)kp * BTILE + lane * 8;
        short* bb = base + ATILE;
#pragma unroll
        for (int j = 0; j < NB; ++j) dma16(wk + j * 512, bb + j * 512);
    };

    float4v acc[CT];
#pragma unroll
    for (int t = 0; t < CT; ++t) acc[t] = (float4v)0.f;

    auto computeTile = [&](int slot) {
        const short* ab = lds + slot * TILE;
        const short* bb = ab + ATILE;
#pragma unroll
        for (int c = 0; c < CH; ++c) {
            short8 af;
            if constexpr (CH == 1)
                af = *(const short8*)(ab + quad * 128 + l16 * 8);
            else
                af = *(const short8*)(ab + (l16 >> 3) * 512 + (l16 & 7) * 64 +
                                      (c * 4 + quad) * 8);
#pragma unroll
            for (int t = 0; t < CT; ++t) {
                short8 bf = *(const short8*)(bb + ((c * 4 + quad) * CO + t * 16 + l16) * 8);
                acc[t] = __builtin_amdgcn_mfma_f32_16x16x32_bf16(af, bf, acc[t], 0, 0, 0);
            }
        }
    };

    // prologue: tiles 0,1 in flight
    issueTile(0, 0);
    issueTile(1, 1);
    int slot = 0;
    for (int k = 0; k < K - 1; ++k) {
        waitcnt_vm<ND>();                 // tile k landed (only k+1[,k+2] outstanding)
        __builtin_amdgcn_sched_barrier(0);
        if (k + 2 < K) issueTile(k + 2, (k + 2) % 3);
        computeTile(slot);
        slot = (slot == 2) ? 0 : slot + 1;
    }
    waitcnt_vm<0>();
    __builtin_amdgcn_sched_barrier(0);
    computeTile(slot);

    // D layout: col = lane&15, row = quad*4 + reg. NT stores: preact consumed once.
    float* st = stats + (size_t)(blockIdx.x & (NREP - 1)) * 128;
#pragma unroll
    for (int t = 0; t < CT; ++t) {
        int col = t * 16 + l16;
#pragma unroll
        for (int r = 0; r < 4; ++r) {
            int orow = m0 + quad * 4 + r;
            if (orow < N) __builtin_nontemporal_store(acc[t][r], &out[(size_t)orow * CO + col]);
        }
        // fused BN stats (invalid rows gathered the zero row -> exact zeros)
        float s = acc[t][0] + acc[t][1] + acc[t][2] + acc[t][3];
        float ss = acc[t][0] * acc[t][0] + acc[t][1] * acc[t][1] + acc[t][2] * acc[t][2] +
                   acc[t][3] * acc[t][3];
        s += __shfl_xor(s, 16);
        s += __shfl_xor(s, 32);
        ss += __shfl_xor(ss, 16);
        ss += __shfl_xor(ss, 32);
        if (lane < 16) {
            atomicAdd(&st[col], s);
            atomicAdd(&st[64 + col], ss);
        }
    }
}

// ---------------- BN apply + ReLU; replica-reduce in LDS prologue ----------------
template <int COUT, int CHPN, bool F32OUT, bool BFOUT>
__global__ __launch_bounds__(256) void bn_apply(const float* __restrict__ x,
                                                const float* __restrict__ stats,
                                                const float* __restrict__ g,
                                                const float* __restrict__ b,
                                                float* __restrict__ fout,
                                                short* __restrict__ bfout, int N) {
    constexpr int CW = BFOUT ? CHPN : COUT;
    __shared__ float ssc[COUT];
    __shared__ float ssh[COUT];
    int tid = threadIdx.x;
    if (tid < COUT) {
        float s = 0.f, q = 0.f;
#pragma unroll
        for (int r = 0; r < NREP; ++r) {
            s += stats[r * 128 + tid];
            q += stats[r * 128 + 64 + tid];
        }
        float inv = 1.0f / (float)N;
        float m = s * inv;
        float v = q * inv - m * m;
        float sc = g[tid] / sqrtf(v + BN_EPS);
        ssc[tid] = sc;
        ssh[tid] = b[tid] - m * sc;
    }
    __syncthreads();
    long i = (long)blockIdx.x * 256 + tid;
    if (i >= (long)N * CW) return;
    int c = (int)(i % CW);
    long n = i / CW;
    float y = 0.f;
    if (c < COUT) {
        y = fmaxf(__builtin_nontemporal_load(&x[n * COUT + c]) * ssc[c] + ssh[c], 0.f);
        if (F32OUT) __builtin_nontemporal_store(y, &fout[n * COUT + c]);
    }
    if (BFOUT) bfout[n * CHPN + c] = f2bf(y);
}

// ---------------- host helpers ----------------

template <int CHP, int CO, int K>
static void conv(const short* fin, const int* rb, const short* wt, float* preact, float* stats,
                 int N, int zrow, hipStream_t stream) {
    dim3 grid((N + 15) / 16);
    hipLaunchKernelGGL((sconv_dma<CHP, CO, K>), grid, dim3(64), 0, stream, fin, rb, wt, preact,
                       stats, N, zrow);
}

template <int COUT, int CHPN, bool F32OUT, bool BFOUT>
static void apply(const float* preact, const float* stats, const float* g, const float* b,
                  float* fout, short* bfout, int N, hipStream_t stream) {
    constexpr int CW = BFOUT ? CHPN : COUT;
    int blocks = (int)(((long)N * CW + 255) / 256);
    hipLaunchKernelGGL((bn_apply<COUT, CHPN, F32OUT, BFOUT>), dim3(blocks), dim3(256), 0, stream,
                       preact, stats, g, b, fout, bfout, N);
}

extern "C" void kernel_launch(void* const* d_in, const int* in_sizes, int n_in, void* d_out,
                              int out_size, void* d_ws, size_t ws_size, hipStream_t stream) {
    const float* features = (const float*)d_in[0];
    const float* W[14];
    const float* G[14];
    const float* Bb[14];
    for (int i = 0; i < 14; ++i) {
        W[i] = (const float*)d_in[1 + 3 * i];
        G[i] = (const float*)d_in[2 + 3 * i];
        Bb[i] = (const float*)d_in[3 + 3 * i];
    }
    const int* coords0 = (const int*)d_in[43];
    const int* coords1 = (const int*)d_in[44];
    const int* coords2 = (const int*)d_in[45];
    const int* coords3 = (const int*)d_in[46];
    const int* rb0 = (const int*)d_in[47];
    const int* rbc1 = (const int*)d_in[48];
    const int* rb1 = (const int*)d_in[49];
    const int* rbc2 = (const int*)d_in[50];
    const int* rb2 = (const int*)d_in[51];
    const int* rbc3 = (const int*)d_in[52];
    const int* rb3 = (const int*)d_in[53];
    const int* rbc4 = (const int*)d_in[54];

    const int N0 = in_sizes[0] / 4;
    const int N1 = in_sizes[44] / 4;
    const int N2 = in_sizes[45] / 4;
    const int N3 = in_sizes[46] / 4;
    const int N4 = in_sizes[54] / 3;

    float* out = (float*)d_out;
    long off = 0;
    float* xyz0 = out + off; off += (long)N0 * 3;
    float* f0   = out + off; off += (long)N0 * 4;
    float* xyz1 = out + off; off += (long)N1 * 3;
    float* f1   = out + off; off += (long)N1 * 32;
    float* xyz2 = out + off; off += (long)N2 * 3;
    float* f2   = out + off; off += (long)N2 * 64;
    float* xyz3 = out + off; off += (long)N3 * 3;
    float* f3   = out + off; off += (long)N3 * 64;
    float* f4   = out + off;

    long maxN = N0;
    if (N1 > maxN) maxN = N1;
    if (N2 > maxN) maxN = N2;
    if (N3 > maxN) maxN = N3;
    if (N4 > maxN) maxN = N4;
    const int zrow = (int)maxN;

    // workspace layout
    float* preact = (float*)d_ws;                         // maxN*64 fp32
    float* statsBase = preact + (size_t)maxN * 64;        // 14 * NREP * 128 fp32
    short* bfA = (short*)(statsBase + 14 * NREP * 128);   // (maxN+1)*64 bf16 (+zero row)
    short* bfB = bfA + (size_t)(maxN + 1) * 64;           // (maxN+1)*64 bf16
    short* wtBase = bfB + (size_t)(maxN + 1) * 64;        // transposed bf16 weights

    static const int KK[14] = {27, 27, 27, 27, 27, 27, 27, 27, 27, 27, 27, 27, 27, 3};
    static const int CI[14] = {4, 16, 16, 32, 32, 32, 64, 64, 64, 64, 64, 64, 64, 64};
    static const int CO[14] = {16, 16, 32, 32, 32, 64, 64, 64, 64, 64, 64, 64, 64, 64};
    short* WT[14];
    PrepAll pd;
    {
        size_t o = 0;
        int cum = 0;
        for (int l = 0; l < 14; ++l) {
            WT[l] = wtBase + o;
            int chp = CI[l] <= 32 ? 32 : 64;
            pd.src[l] = W[l];
            pd.dst[l] = WT[l];
            pd.CI[l] = CI[l];
            pd.CO[l] = CO[l];
            pd.CHP[l] = chp;
            pd.cum[l] = cum;
            cum += KK[l] * CO[l] * chp;
            o += (size_t)KK[l] * CO[l] * chp;
        }
        pd.cum[14] = cum;
    }

    // zero BN stat slots + zero rows
    int nstats = 14 * NREP * 128;
    hipLaunchKernelGGL(zero_kernel, dim3((nstats + 255) / 256), dim3(256), 0, stream, statsBase,
                       nstats);
    hipLaunchKernelGGL(zero_rows_kernel, dim3(1), dim3(256), 0, stream, bfA, bfB, maxN);

    // prep all weights in one launch
    hipLaunchKernelGGL(prep_all_kernel, dim3((pd.cum[14] + 255) / 256), dim3(256), 0, stream, pd);

    // passthrough outputs
    hipLaunchKernelGGL(copy_kernel, dim3((N0 * 4 + 255) / 256), dim3(256), 0, stream, features, f0,
                       N0 * 4);
    hipLaunchKernelGGL(xyz_kernel, dim3((N0 + 255) / 256), dim3(256), 0, stream, coords0, xyz0, N0,
                       0.05f, 0.05f, 0.1f);
    hipLaunchKernelGGL(xyz_kernel, dim3((N1 + 255) / 256), dim3(256), 0, stream, coords1, xyz1, N1,
                       0.1f, 0.1f, 0.2f);
    hipLaunchKernelGGL(xyz_kernel, dim3((N2 + 255) / 256), dim3(256), 0, stream, coords2, xyz2, N2,
                       0.2f, 0.2f, 0.4f);
    hipLaunchKernelGGL(xyz_kernel, dim3((N3 + 255) / 256), dim3(256), 0, stream, coords3, xyz3, N3,
                       0.4f, 0.4f, 0.8f);

    // f0 -> bf16 padded
    hipLaunchKernelGGL(convert_f0, dim3((N0 * 32 + 255) / 256), dim3(256), 0, stream, features,
                       bfA, N0);

    float* st = statsBase;
#define STAT(l) (st + (size_t)(l)*NREP * 128)

    // stage 1
    conv<32, 16, 27>(bfA, rb0, WT[0], preact, STAT(0), N0, zrow, stream);
    apply<16, 32, false, true>(preact, STAT(0), G[0], Bb[0], nullptr, bfB, N0, stream);
    conv<32, 16, 27>(bfB, rb0, WT[1], preact, STAT(1), N0, zrow, stream);
    apply<16, 32, false, true>(preact, STAT(1), G[1], Bb[1], nullptr, bfA, N0, stream);
    conv<32, 32, 27>(bfA, rbc1, WT[2], preact, STAT(2), N1, zrow, stream);
    apply<32, 32, true, true>(preact, STAT(2), G[2], Bb[2], f1, bfB, N1, stream);
    // stage 2
    conv<32, 32, 27>(bfB, rb1, WT[3], preact, STAT(3), N1, zrow, stream);
    apply<32, 32, false, true>(preact, STAT(3), G[3], Bb[3], nullptr, bfA, N1, stream);
    conv<32, 32, 27>(bfA, rb1, WT[4], preact, STAT(4), N1, zrow, stream);
    apply<32, 32, false, true>(preact, STAT(4), G[4], Bb[4], nullptr, bfB, N1, stream);
    conv<32, 64, 27>(bfB, rbc2, WT[5], preact, STAT(5), N2, zrow, stream);
    apply<64, 64, true, true>(preact, STAT(5), G[5], Bb[5], f2, bfA, N2, stream);
    // stage 3
    conv<64, 64, 27>(bfA, rb2, WT[6], preact, STAT(6), N2, zrow, stream);
    apply<64, 64, false, true>(preact, STAT(6), G[6], Bb[6], nullptr, bfB, N2, stream);
    conv<64, 64, 27>(bfB, rb2, WT[7], preact, STAT(7), N2, zrow, stream);
    apply<64, 64, false, true>(preact, STAT(7), G[7], Bb[7], nullptr, bfA, N2, stream);
    conv<64, 64, 27>(bfA, rb2, WT[8], preact, STAT(8), N2, zrow, stream);
    apply<64, 64, false, true>(preact, STAT(8), G[8], Bb[8], nullptr, bfB, N2, stream);
    conv<64, 64, 27>(bfB, rbc3, WT[9], preact, STAT(9), N3, zrow, stream);
    apply<64, 64, true, true>(preact, STAT(9), G[9], Bb[9], f3, bfA, N3, stream);
    // stage 4
    conv<64, 64, 27>(bfA, rb3, WT[10], preact, STAT(10), N3, zrow, stream);
    apply<64, 64, false, true>(preact, STAT(10), G[10], Bb[10], nullptr, bfB, N3, stream);
    conv<64, 64, 27>(bfB, rb3, WT[11], preact, STAT(11), N3, zrow, stream);
    apply<64, 64, false, true>(preact, STAT(11), G[11], Bb[11], nullptr, bfA, N3, stream);
    conv<64, 64, 27>(bfA, rb3, WT[12], preact, STAT(12), N3, zrow, stream);
    apply<64, 64, false, true>(preact, STAT(12), G[12], Bb[12], nullptr, bfB, N3, stream);
    conv<64, 64, 3>(bfB, rbc4, WT[13], preact, STAT(13), N4, zrow, stream);
    apply<64, 64, true, false>(preact, STAT(13), G[13], Bb[13], f4, nullptr, N4, stream);
#undef STAT
}

// Round 9
// 913.414 us; speedup vs baseline: 1.6032x; 1.2462x over previous
//
#include <hip/hip_runtime.h>

#define BN_EPS 1e-3f
#define NREP 16  // BN stat replicas

typedef __attribute__((ext_vector_type(8))) short short8;
typedef __attribute__((ext_vector_type(4))) float float4v;

__device__ __forceinline__ short f2bf(float f) {
    unsigned u = __float_as_uint(f);
    unsigned r = (u + 0x7FFFu + ((u >> 16) & 1u)) >> 16;
    return (short)r;
}

// s_waitcnt vmcnt(N) only (lgkm/exp unconstrained)
template <int N>
__device__ __forceinline__ void waitcnt_vm() {
    __builtin_amdgcn_s_waitcnt(0xF70 | (N & 15) | ((N >> 4) << 14));
}

// raw s_barrier: no compiler-inserted vmcnt(0) drain (we wait explicitly)
__device__ __forceinline__ void wave_barrier() { asm volatile("s_barrier" ::: "memory"); }

// async global -> LDS, 16B/lane; lds dst wave-uniform base + lane*16
__device__ __forceinline__ void dma16(const short* g, short* l) {
    __builtin_amdgcn_global_load_lds((const __attribute__((address_space(1))) void*)g,
                                     (__attribute__((address_space(3))) void*)l, 16, 0, 0);
}

// ---------------- small utility kernels ----------------

__global__ __launch_bounds__(256) void zero_kernel(float* p, int n) {
    int i = blockIdx.x * 256 + threadIdx.x;
    if (i < n) p[i] = 0.f;
}

__global__ __launch_bounds__(256) void copy_kernel(const float* __restrict__ in,
                                                   float* __restrict__ out, int n) {
    int i = blockIdx.x * 256 + threadIdx.x;
    if (i < n) out[i] = in[i];
}

// zero the "zero rows" (index maxN) of both bf16 buffers at both strides
__global__ __launch_bounds__(256) void zero_rows_kernel(short* a, short* b, long maxN) {
    int t = threadIdx.x;
    if (t < 32) a[maxN * 32 + t] = 0;
    else if (t < 96) a[maxN * 64 + (t - 32)] = 0;
    else if (t < 128) b[maxN * 32 + (t - 96)] = 0;
    else if (t < 192) b[maxN * 64 + (t - 128)] = 0;
}

// coords rows are (b, z, y, x); xyz = (x,y,z) * (voxel*stride) + (0,-40,-3)
__global__ __launch_bounds__(256) void xyz_kernel(const int* __restrict__ coords,
                                                  float* __restrict__ out, int N,
                                                  float sx, float sy, float sz) {
    int n = blockIdx.x * 256 + threadIdx.x;
    if (n >= N) return;
    int4 c = ((const int4*)coords)[n];
    out[n * 3 + 0] = c.w * sx;
    out[n * 3 + 1] = c.z * sy - 40.0f;
    out[n * 3 + 2] = c.y * sz - 3.0f;
}

// f0 (N x 4 fp32) -> bf16 padded (N x 32)
__global__ __launch_bounds__(256) void convert_f0(const float* __restrict__ f,
                                                  short* __restrict__ dst, int N) {
    int i = blockIdx.x * 256 + threadIdx.x;
    if (i >= N * 32) return;
    int c = i & 31, n = i >> 5;
    dst[i] = (c < 4) ? f2bf(f[n * 4 + c]) : (short)0;
}

// ---- weight prep: W [K][CI][CO] fp32 -> Wt [K][c*CT+t][quad][l16][8] bf16 ----
// so that each 1KB DMA chunk == one contiguous conflict-free b128 read group.
struct PrepAll {
    const float* src[14];
    short* dst[14];
    int CI[14];
    int CO[14];
    int CHP[14];
    int cum[15];
};

__global__ __launch_bounds__(256) void prep_all_kernel(PrepAll d) {
    int i = blockIdx.x * 256 + threadIdx.x;
    if (i >= d.cum[14]) return;
    int l = 0;
    while (l < 13 && i >= d.cum[l + 1]) ++l;
    int f = i - d.cum[l];
    int CO = d.CO[l], CI = d.CI[l];
    int NCH = d.CHP[l] / 32, CT = CO / 16;
    int e = f & 7;
    int u = f >> 3;
    int l16 = u & 15;
    int q = (u >> 4) & 3;
    int u2 = u >> 6;
    int t = u2 % CT;
    int c = (u2 / CT) % NCH;
    int k = u2 / (CT * NCH);
    int ci = c * 32 + q * 8 + e;
    int co = t * 16 + l16;
    float v = (ci < CI) ? d.src[l][((size_t)k * CI + ci) * CO + co] : 0.f;
    d.dst[l][i - d.cum[l] + 0] = f2bf(v);
    d.dst[l][f] = f2bf(v);
}

// ---------------- DMA-ring MFMA sparse conv: 4 waves/block, 64 rows x CO ----------
// feat: bf16 [Nin+1][CHP] (row zrow = zeros); Wt: swizzled bf16; rb: [K][N].
// Per k: each wave DMAs its own 16-row A subtile + its share of the common B tile.
// Ring of 3 tiles, per-wave vmcnt waits on OWN DMAs + raw s_barrier (no drain).
template <int CHP, int CO, int K>
__global__ __launch_bounds__(256) void sconv_dma(const short* __restrict__ feat,
                                                 const int* __restrict__ rb,
                                                 const short* __restrict__ Wt,
                                                 float* __restrict__ out,
                                                 float* __restrict__ stats, int N, int zrow) {
    constexpr int NCH = CHP / 32;          // 32-ci chunks
    constexpr int CT = CO / 16;            // col tiles
    constexpr int AT_W = 16 * CHP;         // shorts, per-wave A subtile
    constexpr int ATILE = 64 * CHP;        // shorts, block A
    constexpr int BTILE = CO * CHP;        // shorts
    constexpr int TILE = ATILE + BTILE;
    constexpr int NA = CHP / 32;           // per-wave A DMA insts (1KB each)
    constexpr int NB = BTILE / 512;        // total B DMA insts
    constexpr int D0 = NA + (NB + 3) / 4;  // per-wave outstanding per tile
    constexpr int D1 = NA + (NB + 2) / 4;
    constexpr int D2 = NA + (NB + 1) / 4;
    constexpr int D3 = NA + NB / 4;

    __shared__ __align__(16) short lds[3 * TILE];
    __shared__ int sIdx[K * 64];

    const int tid = threadIdx.x;
    const int w = tid >> 6;       // wave id (uniform per wave)
    const int lane = tid & 63;
    const int quad = lane >> 4;
    const int l16 = lane & 15;
    const int m0 = blockIdx.x * 64;

    for (int e = tid; e < K * 64; e += 256) {
        int r = m0 + (e & 63);
        sIdx[e] = (r < N) ? rb[(size_t)(e >> 6) * N + r] : -1;
    }
    __syncthreads();

    auto issueTile = [&](int kp, int slot) {
        short* base = lds + slot * TILE;
        short* aw = base + w * AT_W;
        const int* sI = &sIdx[kp * 64 + w * 16];
        int row = sI[lane & 15];
        const short* fr = feat + (size_t)(row < 0 ? zrow : row) * CHP + (lane >> 4) * 8;
#pragma unroll
        for (int j = 0; j < NA; ++j) dma16(fr + j * 32, aw + j * 512);
        short* bb = base + ATILE;
        const short* wk = Wt + (size_t)kp * BTILE + lane * 8;
#pragma unroll
        for (int j = 0; j < NB; ++j)
            if ((j & 3) == w) dma16(wk + j * 512, bb + j * 512);
    };

    auto waitTile = [&]() {
        if constexpr ((NB & 3) == 0) {
            waitcnt_vm<D0>();
        } else {
            if (w == 0) waitcnt_vm<D0>();
            else if (w == 1) waitcnt_vm<D1>();
            else if (w == 2) waitcnt_vm<D2>();
            else waitcnt_vm<D3>();
        }
        __builtin_amdgcn_sched_barrier(0);
    };

    float4v acc[CT];
#pragma unroll
    for (int t = 0; t < CT; ++t) acc[t] = (float4v)0.f;

    auto computeTile = [&](int slot) {
        const short* aw = lds + slot * TILE + w * AT_W;
        const short* bb = lds + slot * TILE + ATILE;
#pragma unroll
        for (int c = 0; c < NCH; ++c) {
            short8 af = *(const short8*)(aw + (c * 64 + quad * 16 + l16) * 8);
#pragma unroll
            for (int t = 0; t < CT; ++t) {
                short8 bf = *(const short8*)(bb + ((c * CT + t) * 64 + quad * 16 + l16) * 8);
                acc[t] = __builtin_amdgcn_mfma_f32_16x16x32_bf16(af, bf, acc[t], 0, 0, 0);
            }
        }
    };

    issueTile(0, 0);
    if constexpr (K > 1) issueTile(1, 1);
    int slot = 0;
    for (int k = 0; k < K - 1; ++k) {
        waitTile();        // own tile-k DMAs landed (tile k+1 still in flight)
        wave_barrier();    // all waves' tile-k landed; all done computing k-1
        if (k + 2 < K) issueTile(k + 2, (k + 2) % 3);  // overwrites slot (k-1): safe
        computeTile(slot);
        slot = (slot == 2) ? 0 : slot + 1;
    }
    waitcnt_vm<0>();
    __builtin_amdgcn_sched_barrier(0);
    wave_barrier();
    computeTile(slot);

    // stores: D layout col = lane&15, row = quad*4 + reg
#pragma unroll
    for (int t = 0; t < CT; ++t) {
        int col = t * 16 + l16;
#pragma unroll
        for (int r = 0; r < 4; ++r) {
            int orow = m0 + w * 16 + quad * 4 + r;
            if (orow < N) __builtin_nontemporal_store(acc[t][r], &out[(size_t)orow * CO + col]);
        }
    }

    // block-level BN stats reduction -> one atomic per channel per block
    __syncthreads();  // all tile reads done; reuse lds as fp32 scratch
    float* red = (float*)lds;  // [4][2*CO]
#pragma unroll
    for (int t = 0; t < CT; ++t) {
        float s = acc[t][0] + acc[t][1] + acc[t][2] + acc[t][3];
        float ss = acc[t][0] * acc[t][0] + acc[t][1] * acc[t][1] + acc[t][2] * acc[t][2] +
                   acc[t][3] * acc[t][3];
        s += __shfl_xor(s, 16);
        s += __shfl_xor(s, 32);
        ss += __shfl_xor(ss, 16);
        ss += __shfl_xor(ss, 32);
        if (lane < 16) {
            red[w * 2 * CO + t * 16 + lane] = s;
            red[w * 2 * CO + CO + t * 16 + lane] = ss;
        }
    }
    __syncthreads();
    if (tid < 2 * CO) {
        float v = red[tid] + red[2 * CO + tid] + red[4 * CO + tid] + red[6 * CO + tid];
        float* st = stats + (size_t)(blockIdx.x & (NREP - 1)) * 128;
        atomicAdd(&st[(tid < CO) ? tid : (64 + tid - CO)], v);
    }
}

// ---------------- BN apply + ReLU; replica-reduce in LDS prologue ----------------
template <int COUT, int CHPN, bool F32OUT, bool BFOUT>
__global__ __launch_bounds__(256) void bn_apply(const float* __restrict__ x,
                                                const float* __restrict__ stats,
                                                const float* __restrict__ g,
                                                const float* __restrict__ b,
                                                float* __restrict__ fout,
                                                short* __restrict__ bfout, int N) {
    constexpr int CW = BFOUT ? CHPN : COUT;
    __shared__ float ssc[COUT];
    __shared__ float ssh[COUT];
    int tid = threadIdx.x;
    if (tid < COUT) {
        float s = 0.f, q = 0.f;
#pragma unroll
        for (int r = 0; r < NREP; ++r) {
            s += stats[r * 128 + tid];
            q += stats[r * 128 + 64 + tid];
        }
        float inv = 1.0f / (float)N;
        float m = s * inv;
        float v = q * inv - m * m;
        float sc = g[tid] / sqrtf(v + BN_EPS);
        ssc[tid] = sc;
        ssh[tid] = b[tid] - m * sc;
    }
    __syncthreads();
    long i = (long)blockIdx.x * 256 + tid;
    if (i >= (long)N * CW) return;
    int c = (int)(i % CW);
    long n = i / CW;
    float y = 0.f;
    if (c < COUT) {
        y = fmaxf(__builtin_nontemporal_load(&x[n * COUT + c]) * ssc[c] + ssh[c], 0.f);
        if (F32OUT) __builtin_nontemporal_store(y, &fout[n * COUT + c]);
    }
    if (BFOUT) bfout[n * CHPN + c] = f2bf(y);
}

// ---------------- host helpers ----------------

template <int CHP, int CO, int K>
static void conv(const short* fin, const int* rb, const short* wt, float* preact, float* stats,
                 int N, int zrow, hipStream_t stream) {
    dim3 grid((N + 63) / 64);
    hipLaunchKernelGGL((sconv_dma<CHP, CO, K>), grid, dim3(256), 0, stream, fin, rb, wt, preact,
                       stats, N, zrow);
}

template <int COUT, int CHPN, bool F32OUT, bool BFOUT>
static void apply(const float* preact, const float* stats, const float* g, const float* b,
                  float* fout, short* bfout, int N, hipStream_t stream) {
    constexpr int CW = BFOUT ? CHPN : COUT;
    int blocks = (int)(((long)N * CW + 255) / 256);
    hipLaunchKernelGGL((bn_apply<COUT, CHPN, F32OUT, BFOUT>), dim3(blocks), dim3(256), 0, stream,
                       preact, stats, g, b, fout, bfout, N);
}

extern "C" void kernel_launch(void* const* d_in, const int* in_sizes, int n_in, void* d_out,
                              int out_size, void* d_ws, size_t ws_size, hipStream_t stream) {
    const float* features = (const float*)d_in[0];
    const float* W[14];
    const float* G[14];
    const float* Bb[14];
    for (int i = 0; i < 14; ++i) {
        W[i] = (const float*)d_in[1 + 3 * i];
        G[i] = (const float*)d_in[2 + 3 * i];
        Bb[i] = (const float*)d_in[3 + 3 * i];
    }
    const int* coords0 = (const int*)d_in[43];
    const int* coords1 = (const int*)d_in[44];
    const int* coords2 = (const int*)d_in[45];
    const int* coords3 = (const int*)d_in[46];
    const int* rb0 = (const int*)d_in[47];
    const int* rbc1 = (const int*)d_in[48];
    const int* rb1 = (const int*)d_in[49];
    const int* rbc2 = (const int*)d_in[50];
    const int* rb2 = (const int*)d_in[51];
    const int* rbc3 = (const int*)d_in[52];
    const int* rb3 = (const int*)d_in[53];
    const int* rbc4 = (const int*)d_in[54];

    const int N0 = in_sizes[0] / 4;
    const int N1 = in_sizes[44] / 4;
    const int N2 = in_sizes[45] / 4;
    const int N3 = in_sizes[46] / 4;
    const int N4 = in_sizes[54] / 3;

    float* out = (float*)d_out;
    long off = 0;
    float* xyz0 = out + off; off += (long)N0 * 3;
    float* f0   = out + off; off += (long)N0 * 4;
    float* xyz1 = out + off; off += (long)N1 * 3;
    float* f1   = out + off; off += (long)N1 * 32;
    float* xyz2 = out + off; off += (long)N2 * 3;
    float* f2   = out + off; off += (long)N2 * 64;
    float* xyz3 = out + off; off += (long)N3 * 3;
    float* f3   = out + off; off += (long)N3 * 64;
    float* f4   = out + off;

    long maxN = N0;
    if (N1 > maxN) maxN = N1;
    if (N2 > maxN) maxN = N2;
    if (N3 > maxN) maxN = N3;
    if (N4 > maxN) maxN = N4;
    const int zrow = (int)maxN;

    float* preact = (float*)d_ws;                         // maxN*64 fp32
    float* statsBase = preact + (size_t)maxN * 64;        // 14 * NREP * 128 fp32
    short* bfA = (short*)(statsBase + 14 * NREP * 128);   // (maxN+1)*64 bf16
    short* bfB = bfA + (size_t)(maxN + 1) * 64;           // (maxN+1)*64 bf16
    short* wtBase = bfB + (size_t)(maxN + 1) * 64;        // swizzled bf16 weights

    static const int KK[14] = {27, 27, 27, 27, 27, 27, 27, 27, 27, 27, 27, 27, 27, 3};
    static const int CI[14] = {4, 16, 16, 32, 32, 32, 64, 64, 64, 64, 64, 64, 64, 64};
    static const int CO[14] = {16, 16, 32, 32, 32, 64, 64, 64, 64, 64, 64, 64, 64, 64};
    short* WT[14];
    PrepAll pd;
    {
        size_t o = 0;
        int cum = 0;
        for (int l = 0; l < 14; ++l) {
            WT[l] = wtBase + o;
            int chp = CI[l] <= 32 ? 32 : 64;
            pd.src[l] = W[l];
            pd.dst[l] = WT[l];
            pd.CI[l] = CI[l];
            pd.CO[l] = CO[l];
            pd.CHP[l] = chp;
            pd.cum[l] = cum;
            cum += KK[l] * CO[l] * chp;
            o += (size_t)KK[l] * CO[l] * chp;
        }
        pd.cum[14] = cum;
    }

    int nstats = 14 * NREP * 128;
    hipLaunchKernelGGL(zero_kernel, dim3((nstats + 255) / 256), dim3(256), 0, stream, statsBase,
                       nstats);
    hipLaunchKernelGGL(zero_rows_kernel, dim3(1), dim3(256), 0, stream, bfA, bfB, maxN);
    hipLaunchKernelGGL(prep_all_kernel, dim3((pd.cum[14] + 255) / 256), dim3(256), 0, stream, pd);

    hipLaunchKernelGGL(copy_kernel, dim3((N0 * 4 + 255) / 256), dim3(256), 0, stream, features, f0,
                       N0 * 4);
    hipLaunchKernelGGL(xyz_kernel, dim3((N0 + 255) / 256), dim3(256), 0, stream, coords0, xyz0, N0,
                       0.05f, 0.05f, 0.1f);
    hipLaunchKernelGGL(xyz_kernel, dim3((N1 + 255) / 256), dim3(256), 0, stream, coords1, xyz1, N1,
                       0.1f, 0.1f, 0.2f);
    hipLaunchKernelGGL(xyz_kernel, dim3((N2 + 255) / 256), dim3(256), 0, stream, coords2, xyz2, N2,
                       0.2f, 0.2f, 0.4f);
    hipLaunchKernelGGL(xyz_kernel, dim3((N3 + 255) / 256), dim3(256), 0, stream, coords3, xyz3, N3,
                       0.4f, 0.4f, 0.8f);
    hipLaunchKernelGGL(convert_f0, dim3((N0 * 32 + 255) / 256), dim3(256), 0, stream, features,
                       bfA, N0);

    float* st = statsBase;
#define STAT(l) (st + (size_t)(l)*NREP * 128)

    conv<32, 16, 27>(bfA, rb0, WT[0], preact, STAT(0), N0, zrow, stream);
    apply<16, 32, false, true>(preact, STAT(0), G[0], Bb[0], nullptr, bfB, N0, stream);
    conv<32, 16, 27>(bfB, rb0, WT[1], preact, STAT(1), N0, zrow, stream);
    apply<16, 32, false, true>(preact, STAT(1), G[1], Bb[1], nullptr, bfA, N0, stream);
    conv<32, 32, 27>(bfA, rbc1, WT[2], preact, STAT(2), N1, zrow, stream);
    apply<32, 32, true, true>(preact, STAT(2), G[2], Bb[2], f1, bfB, N1, stream);

    conv<32, 32, 27>(bfB, rb1, WT[3], preact, STAT(3), N1, zrow, stream);
    apply<32, 32, false, true>(preact, STAT(3), G[3], Bb[3], nullptr, bfA, N1, stream);
    conv<32, 32, 27>(bfA, rb1, WT[4], preact, STAT(4), N1, zrow, stream);
    apply<32, 32, false, true>(preact, STAT(4), G[4], Bb[4], nullptr, bfB, N1, stream);
    conv<32, 64, 27>(bfB, rbc2, WT[5], preact, STAT(5), N2, zrow, stream);
    apply<64, 64, true, true>(preact, STAT(5), G[5], Bb[5], f2, bfA, N2, stream);

    conv<64, 64, 27>(bfA, rb2, WT[6], preact, STAT(6), N2, zrow, stream);
    apply<64, 64, false, true>(preact, STAT(6), G[6], Bb[6], nullptr, bfB, N2, stream);
    conv<64, 64, 27>(bfB, rb2, WT[7], preact, STAT(7), N2, zrow, stream);
    apply<64, 64, false, true>(preact, STAT(7), G[7], Bb[7], nullptr, bfA, N2, stream);
    conv<64, 64, 27>(bfA, rb2, WT[8], preact, STAT(8), N2, zrow, stream);
    apply<64, 64, false, true>(preact, STAT(8), G[8], Bb[8], nullptr, bfB, N2, stream);
    conv<64, 64, 27>(bfB, rbc3, WT[9], preact, STAT(9), N3, zrow, stream);
    apply<64, 64, true, true>(preact, STAT(9), G[9], Bb[9], f3, bfA, N3, stream);

    conv<64, 64, 27>(bfA, rb3, WT[10], preact, STAT(10), N3, zrow, stream);
    apply<64, 64, false, true>(preact, STAT(10), G[10], Bb[10], nullptr, bfB, N3, stream);
    conv<64, 64, 27>(bfB, rb3, WT[11], preact, STAT(11), N3, zrow, stream);
    apply<64, 64, false, true>(preact, STAT(11), G[11], Bb[11], nullptr, bfA, N3, stream);
    conv<64, 64, 27>(bfA, rb3, WT[12], preact, STAT(12), N3, zrow, stream);
    apply<64, 64, false, true>(preact, STAT(12), G[12], Bb[12], nullptr, bfB, N3, stream);
    conv<64, 64, 3>(bfB, rbc4, WT[13], preact, STAT(13), N4, zrow, stream);
    apply<64, 64, true, false>(preact, STAT(13), G[13], Bb[13], f4, nullptr, N4, stream);
#undef STAT
}

// Round 10
// 787.450 us; speedup vs baseline: 1.8596x; 1.1600x over previous
//
#include <hip/hip_runtime.h>

#define BN_EPS 1e-3f
#define NREP 16  // BN stat replicas

typedef __attribute__((ext_vector_type(8))) short short8;
typedef __attribute__((ext_vector_type(4))) float float4v;

__device__ __forceinline__ short f2bf(float f) {
    unsigned u = __float_as_uint(f);
    unsigned r = (u + 0x7FFFu + ((u >> 16) & 1u)) >> 16;
    return (short)r;
}

// s_waitcnt vmcnt(N) only
template <int N>
__device__ __forceinline__ void waitcnt_vm() {
    __builtin_amdgcn_s_waitcnt(0xF70 | (N & 15) | ((N >> 4) << 14));
}

// raw s_barrier (no compiler vmcnt(0) drain; we wait explicitly)
__device__ __forceinline__ void wave_barrier() { asm volatile("s_barrier" ::: "memory"); }

// async global -> LDS, 16B/lane; lds dst wave-uniform base + lane*16
__device__ __forceinline__ void dma16(const short* g, short* l) {
    __builtin_amdgcn_global_load_lds((const __attribute__((address_space(1))) void*)g,
                                     (__attribute__((address_space(3))) void*)l, 16, 0, 0);
}

// ---------------- small utility kernels ----------------

__global__ __launch_bounds__(256) void zero_kernel(float* p, int n) {
    int i = blockIdx.x * 256 + threadIdx.x;
    if (i < n) p[i] = 0.f;
}

__global__ __launch_bounds__(256) void copy_kernel(const float* __restrict__ in,
                                                   float* __restrict__ out, int n) {
    int i = blockIdx.x * 256 + threadIdx.x;
    if (i < n) out[i] = in[i];
}

__global__ __launch_bounds__(256) void zero_rows_kernel(short* a, short* b, long maxN) {
    int t = threadIdx.x;
    if (t < 32) a[maxN * 32 + t] = 0;
    else if (t < 96) a[maxN * 64 + (t - 32)] = 0;
    else if (t < 128) b[maxN * 32 + (t - 96)] = 0;
    else if (t < 192) b[maxN * 64 + (t - 128)] = 0;
}

__global__ __launch_bounds__(256) void xyz_kernel(const int* __restrict__ coords,
                                                  float* __restrict__ out, int N,
                                                  float sx, float sy, float sz) {
    int n = blockIdx.x * 256 + threadIdx.x;
    if (n >= N) return;
    int4 c = ((const int4*)coords)[n];
    out[n * 3 + 0] = c.w * sx;
    out[n * 3 + 1] = c.z * sy - 40.0f;
    out[n * 3 + 2] = c.y * sz - 3.0f;
}

__global__ __launch_bounds__(256) void convert_f0(const float* __restrict__ f,
                                                  short* __restrict__ dst, int N) {
    int i = blockIdx.x * 256 + threadIdx.x;
    if (i >= N * 32) return;
    int c = i & 31, n = i >> 5;
    dst[i] = (c < 4) ? f2bf(f[n * 4 + c]) : (short)0;
}

// ---- weight prep: W [K][CI][CO] fp32 -> Wt [K][c*CT+t][quad][l16][8] bf16 ----
struct PrepAll {
    const float* src[14];
    short* dst[14];
    int CI[14];
    int CO[14];
    int CHP[14];
    int cum[15];
};

__global__ __launch_bounds__(256) void prep_all_kernel(PrepAll d) {
    int i = blockIdx.x * 256 + threadIdx.x;
    if (i >= d.cum[14]) return;
    int l = 0;
    while (l < 13 && i >= d.cum[l + 1]) ++l;
    int f = i - d.cum[l];
    int CO = d.CO[l], CI = d.CI[l];
    int NCH = d.CHP[l] / 32, CT = CO / 16;
    int e = f & 7;
    int u = f >> 3;
    int l16 = u & 15;
    int q = (u >> 4) & 3;
    int u2 = u >> 6;
    int t = u2 % CT;
    int c = (u2 / CT) % NCH;
    int k = u2 / (CT * NCH);
    int ci = c * 32 + q * 8 + e;
    int co = t * 16 + l16;
    float v = (ci < CI) ? d.src[l][((size_t)k * CI + ci) * CO + co] : 0.f;
    d.dst[l][f] = f2bf(v);
}

// per-k A fragments for one wave (32 rows x CHP), held in VGPRs (named members
// -> phi rotation, no arrays, nothing for the allocator to demote)
struct ASet {
    short8 v0, v1, v2, v3;  // (mt0,c0) (mt0,c1) (mt1,c0) (mt1,c1)
};

// ---------------- hybrid MFMA sparse conv: 4 waves x 32 rows, B-only LDS ring ------
// A: direct global->VGPR gathers (lane layout == MFMA A-frag), depth-2 pipeline.
// B: 3-slot LDS ring via global_load_lds, split across waves.
// vmcnt discipline: per tile issue [B(b_w) then A(2*NCH)]; wait vmcnt(b_w+a).
template <int CHP, int CO, int K>
__global__ __launch_bounds__(256, 4) void sconv_hyb(const short* __restrict__ feat,
                                                    const int* __restrict__ rb,
                                                    const short* __restrict__ Wt,
                                                    float* __restrict__ out,
                                                    float* __restrict__ stats, int N, int zrow) {
    constexpr int NCH = CHP / 32;
    constexpr int CT = CO / 16;
    constexpr int BTILE = CO * CHP;    // shorts
    constexpr int NB = BTILE / 512;    // B DMA insts per tile (1KB each)
    constexpr int A = 2 * NCH;         // A loads per wave per tile
    constexpr int ROWS = 128;

    __shared__ __align__(16) short ldsB[3 * BTILE];
    __shared__ int sIdx[K * ROWS];

    const int tid = threadIdx.x;
    const int w = tid >> 6;
    const int lane = tid & 63;
    const int quad = lane >> 4;
    const int l16 = lane & 15;
    const int m0 = blockIdx.x * ROWS;

    for (int e = tid; e < K * ROWS; e += 256) {
        int r = m0 + (e & (ROWS - 1));
        sIdx[e] = (r < N) ? __builtin_nontemporal_load(&rb[(size_t)(e >> 7) * N + r]) : -1;
    }
    __syncthreads();

    const short* fquad = feat + quad * 8;

    auto issueB = [&](int kp, int slot) {
        const short* wk = Wt + (size_t)kp * BTILE + lane * 8;
        short* bb = ldsB + slot * BTILE;
#pragma unroll
        for (int jj = 0; jj < (NB + 3) / 4; ++jj) {
            int j = jj * 4 + w;
            if (j < NB) dma16(wk + j * 512, bb + j * 512);
        }
    };
    auto issueA = [&](int kp) {
        ASet s;
        int i0 = sIdx[kp * ROWS + w * 32 + l16];
        int i1 = sIdx[kp * ROWS + w * 32 + 16 + l16];
        const short* p0 = fquad + (size_t)(i0 < 0 ? zrow : i0) * CHP;
        const short* p1 = fquad + (size_t)(i1 < 0 ? zrow : i1) * CHP;
        s.v0 = *(const short8*)p0;
        s.v2 = *(const short8*)p1;
        if constexpr (NCH == 2) {
            s.v1 = *(const short8*)(p0 + 32);
            s.v3 = *(const short8*)(p1 + 32);
        } else {
            s.v1 = (short8)0;
            s.v3 = (short8)0;
        }
        return s;
    };

    float4v acc[2][CT];
#pragma unroll
    for (int mt = 0; mt < 2; ++mt)
#pragma unroll
        for (int t = 0; t < CT; ++t) acc[mt][t] = (float4v)0.f;

    // per-wave wait constant: own B share + own A loads (one tile's worth)
    constexpr int BW0 = NB / 4 + ((NB % 4) > 0 ? 1 : 0);
    constexpr int BW1 = NB / 4 + ((NB % 4) > 1 ? 1 : 0);
    constexpr int BW2 = NB / 4 + ((NB % 4) > 2 ? 1 : 0);
    constexpr int BW3 = NB / 4;

    // prologue: tiles 0,1 in flight (order per tile: B then A)
    issueB(0, 0);
    ASet sA = issueA(0);
    issueB(1, 1);
    ASet sB = issueA(1);
    ASet sC;

    int slotRd = 0, slotWr = 2;
    for (int k = 0; k < K; ++k) {
        if (k < K - 1) {
            if (w == 0) waitcnt_vm<BW0 + A>();
            else if (w == 1) waitcnt_vm<BW1 + A>();
            else if (w == 2) waitcnt_vm<BW2 + A>();
            else waitcnt_vm<BW3 + A>();
        } else {
            waitcnt_vm<0>();
        }
        __builtin_amdgcn_sched_barrier(0);
        wave_barrier();  // all waves' B(k) halves landed; all done reading slot k-1
        if (k + 2 < K) {
            issueB(k + 2, slotWr);
            sC = issueA(k + 2);
        }
        // compute tile k: B from LDS slot, A from sA registers
        const short* bb = ldsB + slotRd * BTILE;
#pragma unroll
        for (int c = 0; c < NCH; ++c) {
#pragma unroll
            for (int t = 0; t < CT; ++t) {
                short8 bf = *(const short8*)(bb + ((c * CT + t) * 64 + quad * 16 + l16) * 8);
#pragma unroll
                for (int mt = 0; mt < 2; ++mt) {
                    short8 af = (mt == 0) ? ((c == 0) ? sA.v0 : sA.v1)
                                          : ((c == 0) ? sA.v2 : sA.v3);
                    acc[mt][t] = __builtin_amdgcn_mfma_f32_16x16x32_bf16(af, bf, acc[mt][t], 0,
                                                                         0, 0);
                }
            }
        }
        sA = sB;
        sB = sC;
        slotRd = (slotRd == 2) ? 0 : slotRd + 1;
        slotWr = (slotWr == 2) ? 0 : slotWr + 1;
    }

    // stores: D layout col = lane&15, row = quad*4 + reg
#pragma unroll
    for (int mt = 0; mt < 2; ++mt)
#pragma unroll
        for (int t = 0; t < CT; ++t) {
            int col = t * 16 + l16;
#pragma unroll
            for (int r = 0; r < 4; ++r) {
                int orow = m0 + w * 32 + mt * 16 + quad * 4 + r;
                if (orow < N)
                    __builtin_nontemporal_store(acc[mt][t][r], &out[(size_t)orow * CO + col]);
            }
        }

    // block-level BN stats -> one atomic per channel per block
    __syncthreads();
    float* red = (float*)ldsB;  // [4][2*CO]
#pragma unroll
    for (int t = 0; t < CT; ++t) {
        float s = 0.f, ss = 0.f;
#pragma unroll
        for (int mt = 0; mt < 2; ++mt)
#pragma unroll
            for (int r = 0; r < 4; ++r) {
                float v = acc[mt][t][r];
                s += v;
                ss += v * v;
            }
        s += __shfl_xor(s, 16);
        s += __shfl_xor(s, 32);
        ss += __shfl_xor(ss, 16);
        ss += __shfl_xor(ss, 32);
        if (lane < 16) {
            red[w * 2 * CO + t * 16 + lane] = s;
            red[w * 2 * CO + CO + t * 16 + lane] = ss;
        }
    }
    __syncthreads();
    if (tid < 2 * CO) {
        float v = red[tid] + red[2 * CO + tid] + red[4 * CO + tid] + red[6 * CO + tid];
        float* st = stats + (size_t)(blockIdx.x & (NREP - 1)) * 128;
        atomicAdd(&st[(tid < CO) ? tid : (64 + tid - CO)], v);
    }
}

// ---------------- BN apply + ReLU; replica-reduce in LDS prologue ----------------
template <int COUT, int CHPN, bool F32OUT, bool BFOUT>
__global__ __launch_bounds__(256) void bn_apply(const float* __restrict__ x,
                                                const float* __restrict__ stats,
                                                const float* __restrict__ g,
                                                const float* __restrict__ b,
                                                float* __restrict__ fout,
                                                short* __restrict__ bfout, int N) {
    constexpr int CW = BFOUT ? CHPN : COUT;
    __shared__ float ssc[COUT];
    __shared__ float ssh[COUT];
    int tid = threadIdx.x;
    if (tid < COUT) {
        float s = 0.f, q = 0.f;
#pragma unroll
        for (int r = 0; r < NREP; ++r) {
            s += stats[r * 128 + tid];
            q += stats[r * 128 + 64 + tid];
        }
        float inv = 1.0f / (float)N;
        float m = s * inv;
        float v = q * inv - m * m;
        float sc = g[tid] / sqrtf(v + BN_EPS);
        ssc[tid] = sc;
        ssh[tid] = b[tid] - m * sc;
    }
    __syncthreads();
    long i = (long)blockIdx.x * 256 + tid;
    if (i >= (long)N * CW) return;
    int c = (int)(i % CW);
    long n = i / CW;
    float y = 0.f;
    if (c < COUT) {
        y = fmaxf(__builtin_nontemporal_load(&x[n * COUT + c]) * ssc[c] + ssh[c], 0.f);
        if (F32OUT) __builtin_nontemporal_store(y, &fout[n * COUT + c]);
    }
    if (BFOUT) bfout[n * CHPN + c] = f2bf(y);
}

// ---------------- host helpers ----------------

template <int CHP, int CO, int K>
static void conv(const short* fin, const int* rb, const short* wt, float* preact, float* stats,
                 int N, int zrow, hipStream_t stream) {
    dim3 grid((N + 127) / 128);
    hipLaunchKernelGGL((sconv_hyb<CHP, CO, K>), grid, dim3(256), 0, stream, fin, rb, wt, preact,
                       stats, N, zrow);
}

template <int COUT, int CHPN, bool F32OUT, bool BFOUT>
static void apply(const float* preact, const float* stats, const float* g, const float* b,
                  float* fout, short* bfout, int N, hipStream_t stream) {
    constexpr int CW = BFOUT ? CHPN : COUT;
    int blocks = (int)(((long)N * CW + 255) / 256);
    hipLaunchKernelGGL((bn_apply<COUT, CHPN, F32OUT, BFOUT>), dim3(blocks), dim3(256), 0, stream,
                       preact, stats, g, b, fout, bfout, N);
}

extern "C" void kernel_launch(void* const* d_in, const int* in_sizes, int n_in, void* d_out,
                              int out_size, void* d_ws, size_t ws_size, hipStream_t stream) {
    const float* features = (const float*)d_in[0];
    const float* W[14];
    const float* G[14];
    const float* Bb[14];
    for (int i = 0; i < 14; ++i) {
        W[i] = (const float*)d_in[1 + 3 * i];
        G[i] = (const float*)d_in[2 + 3 * i];
        Bb[i] = (const float*)d_in[3 + 3 * i];
    }
    const int* coords0 = (const int*)d_in[43];
    const int* coords1 = (const int*)d_in[44];
    const int* coords2 = (const int*)d_in[45];
    const int* coords3 = (const int*)d_in[46];
    const int* rb0 = (const int*)d_in[47];
    const int* rbc1 = (const int*)d_in[48];
    const int* rb1 = (const int*)d_in[49];
    const int* rbc2 = (const int*)d_in[50];
    const int* rb2 = (const int*)d_in[51];
    const int* rbc3 = (const int*)d_in[52];
    const int* rb3 = (const int*)d_in[53];
    const int* rbc4 = (const int*)d_in[54];

    const int N0 = in_sizes[0] / 4;
    const int N1 = in_sizes[44] / 4;
    const int N2 = in_sizes[45] / 4;
    const int N3 = in_sizes[46] / 4;
    const int N4 = in_sizes[54] / 3;

    float* out = (float*)d_out;
    long off = 0;
    float* xyz0 = out + off; off += (long)N0 * 3;
    float* f0   = out + off; off += (long)N0 * 4;
    float* xyz1 = out + off; off += (long)N1 * 3;
    float* f1   = out + off; off += (long)N1 * 32;
    float* xyz2 = out + off; off += (long)N2 * 3;
    float* f2   = out + off; off += (long)N2 * 64;
    float* xyz3 = out + off; off += (long)N3 * 3;
    float* f3   = out + off; off += (long)N3 * 64;
    float* f4   = out + off;

    long maxN = N0;
    if (N1 > maxN) maxN = N1;
    if (N2 > maxN) maxN = N2;
    if (N3 > maxN) maxN = N3;
    if (N4 > maxN) maxN = N4;
    const int zrow = (int)maxN;

    float* preact = (float*)d_ws;                         // maxN*64 fp32
    float* statsBase = preact + (size_t)maxN * 64;        // 14 * NREP * 128 fp32
    short* bfA = (short*)(statsBase + 14 * NREP * 128);   // (maxN+1)*64 bf16
    short* bfB = bfA + (size_t)(maxN + 1) * 64;           // (maxN+1)*64 bf16
    short* wtBase = bfB + (size_t)(maxN + 1) * 64;        // swizzled bf16 weights

    static const int KK[14] = {27, 27, 27, 27, 27, 27, 27, 27, 27, 27, 27, 27, 27, 3};
    static const int CI[14] = {4, 16, 16, 32, 32, 32, 64, 64, 64, 64, 64, 64, 64, 64};
    static const int CO[14] = {16, 16, 32, 32, 32, 64, 64, 64, 64, 64, 64, 64, 64, 64};
    short* WT[14];
    PrepAll pd;
    {
        size_t o = 0;
        int cum = 0;
        for (int l = 0; l < 14; ++l) {
            WT[l] = wtBase + o;
            int chp = CI[l] <= 32 ? 32 : 64;
            pd.src[l] = W[l];
            pd.dst[l] = WT[l];
            pd.CI[l] = CI[l];
            pd.CO[l] = CO[l];
            pd.CHP[l] = chp;
            pd.cum[l] = cum;
            cum += KK[l] * CO[l] * chp;
            o += (size_t)KK[l] * CO[l] * chp;
        }
        pd.cum[14] = cum;
    }

    int nstats = 14 * NREP * 128;
    hipLaunchKernelGGL(zero_kernel, dim3((nstats + 255) / 256), dim3(256), 0, stream, statsBase,
                       nstats);
    hipLaunchKernelGGL(zero_rows_kernel, dim3(1), dim3(256), 0, stream, bfA, bfB, maxN);
    hipLaunchKernelGGL(prep_all_kernel, dim3((pd.cum[14] + 255) / 256), dim3(256), 0, stream, pd);

    hipLaunchKernelGGL(copy_kernel, dim3((N0 * 4 + 255) / 256), dim3(256), 0, stream, features, f0,
                       N0 * 4);
    hipLaunchKernelGGL(xyz_kernel, dim3((N0 + 255) / 256), dim3(256), 0, stream, coords0, xyz0, N0,
                       0.05f, 0.05f, 0.1f);
    hipLaunchKernelGGL(xyz_kernel, dim3((N1 + 255) / 256), dim3(256), 0, stream, coords1, xyz1, N1,
                       0.1f, 0.1f, 0.2f);
    hipLaunchKernelGGL(xyz_kernel, dim3((N2 + 255) / 256), dim3(256), 0, stream, coords2, xyz2, N2,
                       0.2f, 0.2f, 0.4f);
    hipLaunchKernelGGL(xyz_kernel, dim3((N3 + 255) / 256), dim3(256), 0, stream, coords3, xyz3, N3,
                       0.4f, 0.4f, 0.8f);
    hipLaunchKernelGGL(convert_f0, dim3((N0 * 32 + 255) / 256), dim3(256), 0, stream, features,
                       bfA, N0);

    float* st = statsBase;
#define STAT(l) (st + (size_t)(l)*NREP * 128)

    conv<32, 16, 27>(bfA, rb0, WT[0], preact, STAT(0), N0, zrow, stream);
    apply<16, 32, false, true>(preact, STAT(0), G[0], Bb[0], nullptr, bfB, N0, stream);
    conv<32, 16, 27>(bfB, rb0, WT[1], preact, STAT(1), N0, zrow, stream);
    apply<16, 32, false, true>(preact, STAT(1), G[1], Bb[1], nullptr, bfA, N0, stream);
    conv<32, 32, 27>(bfA, rbc1, WT[2], preact, STAT(2), N1, zrow, stream);
    apply<32, 32, true, true>(preact, STAT(2), G[2], Bb[2], f1, bfB, N1, stream);

    conv<32, 32, 27>(bfB, rb1, WT[3], preact, STAT(3), N1, zrow, stream);
    apply<32, 32, false, true>(preact, STAT(3), G[3], Bb[3], nullptr, bfA, N1, stream);
    conv<32, 32, 27>(bfA, rb1, WT[4], preact, STAT(4), N1, zrow, stream);
    apply<32, 32, false, true>(preact, STAT(4), G[4], Bb[4], nullptr, bfB, N1, stream);
    conv<32, 64, 27>(bfB, rbc2, WT[5], preact, STAT(5), N2, zrow, stream);
    apply<64, 64, true, true>(preact, STAT(5), G[5], Bb[5], f2, bfA, N2, stream);

    conv<64, 64, 27>(bfA, rb2, WT[6], preact, STAT(6), N2, zrow, stream);
    apply<64, 64, false, true>(preact, STAT(6), G[6], Bb[6], nullptr, bfB, N2, stream);
    conv<64, 64, 27>(bfB, rb2, WT[7], preact, STAT(7), N2, zrow, stream);
    apply<64, 64, false, true>(preact, STAT(7), G[7], Bb[7], nullptr, bfA, N2, stream);
    conv<64, 64, 27>(bfA, rb2, WT[8], preact, STAT(8), N2, zrow, stream);
    apply<64, 64, false, true>(preact, STAT(8), G[8], Bb[8], nullptr, bfB, N2, stream);
    conv<64, 64, 27>(bfB, rbc3, WT[9], preact, STAT(9), N3, zrow, stream);
    apply<64, 64, true, true>(preact, STAT(9), G[9], Bb[9], f3, bfA, N3, stream);

    conv<64, 64, 27>(bfA, rb3, WT[10], preact, STAT(10), N3, zrow, stream);
    apply<64, 64, false, true>(preact, STAT(10), G[10], Bb[10], nullptr, bfB, N3, stream);
    conv<64, 64, 27>(bfB, rb3, WT[11], preact, STAT(11), N3, zrow, stream);
    apply<64, 64, false, true>(preact, STAT(11), G[11], Bb[11], nullptr, bfA, N3, stream);
    conv<64, 64, 27>(bfA, rb3, WT[12], preact, STAT(12), N3, zrow, stream);
    apply<64, 64, false, true>(preact, STAT(12), G[12], Bb[12], nullptr, bfB, N3, stream);
    conv<64, 64, 3>(bfB, rbc4, WT[13], preact, STAT(13), N4, zrow, stream);
    apply<64, 64, true, false>(preact, STAT(13), G[13], Bb[13], f4, nullptr, N4, stream);
#undef STAT
}